// Round 2
// baseline (2044.735 us; speedup 1.0000x reference)
//
#include <hip/hip_runtime.h>
#include <math.h>

// GridGNN: 3x GATConv(H=4,C=32,concat) + ELU between, then node-level MLP head
// (loc_logits) and graph-pool MLP head (class_logits).
// Strategy: build CSR by dst once (counting sort), wave-per-node softmax+gather.

constexpr int SCAN_TILE = 2048;  // 256 threads * 8 elements

// ---------- CSR build ----------
__global__ void init_cnt_kernel(int* cnt, float* mean_acc, int n) {
  int i = blockIdx.x * blockDim.x + threadIdx.x;
  if (i < n) cnt[i] = 1;  // every node gets one self-loop
  if (blockIdx.x == 0 && threadIdx.x < 16) mean_acc[threadIdx.x] = 0.f;
}

__global__ void count_kernel(const int* __restrict__ dst, int* cnt, int E) {
  int stride = gridDim.x * blockDim.x;
  for (int e = blockIdx.x * blockDim.x + threadIdx.x; e < E; e += stride)
    atomicAdd(&cnt[dst[e]], 1);
}

__global__ void scan1_kernel(const int* __restrict__ cnt, int* rowptr, int* bsum, int n) {
  __shared__ int part[256];
  int t = threadIdx.x, b = blockIdx.x;
  int base = b * SCAN_TILE + t * 8;
  int v[8];
  int s = 0;
#pragma unroll
  for (int i = 0; i < 8; ++i) {
    int idx = base + i;
    v[i] = (idx < n) ? cnt[idx] : 0;
    s += v[i];
  }
  part[t] = s;
  __syncthreads();
  if (t == 0) {
    int run = 0;
    for (int i = 0; i < 256; ++i) { int x = part[i]; part[i] = run; run += x; }
    bsum[b] = run;
  }
  __syncthreads();
  int run = part[t];
#pragma unroll
  for (int i = 0; i < 8; ++i) {
    int idx = base + i;
    run += v[i];
    if (idx < n) rowptr[idx + 1] = run;
  }
}

__global__ void scan2_kernel(int* bsum, int nb, int* rowptr) {
  if (threadIdx.x == 0 && blockIdx.x == 0) {
    rowptr[0] = 0;
    int run = 0;
    for (int b = 0; b < nb; ++b) { int x = bsum[b]; bsum[b] = run; run += x; }
  }
}

__global__ void scan3_kernel(const int* __restrict__ bsum, int* rowptr, int n) {
  int off = bsum[blockIdx.x];
  int base = blockIdx.x * SCAN_TILE + threadIdx.x * 8;
#pragma unroll
  for (int i = 0; i < 8; ++i) {
    int idx = base + i;
    if (idx < n) rowptr[idx + 1] += off;
  }
}

__global__ void copy_cursor_kernel(const int* __restrict__ rowptr, int* cursor, int n) {
  int i = blockIdx.x * blockDim.x + threadIdx.x;
  if (i < n) cursor[i] = rowptr[i];
}

__global__ void scatter_kernel(const int* __restrict__ ei, int* cursor,
                               int* esrc, int* eeid, int E, int n) {
  int stride = gridDim.x * blockDim.x;
  int total = E + n;
  for (int i = blockIdx.x * blockDim.x + threadIdx.x; i < total; i += stride) {
    int s, d, id;
    if (i < E) { s = ei[i]; d = ei[E + i]; id = i; }
    else       { s = i - E; d = s; id = E; }  // self loop; le row E = self le
    int pos = atomicAdd(&cursor[d], 1);
    esrc[pos] = s;
    eeid[pos] = id;
  }
}

// ---------- edge_attr mean (for self-loop fill) ----------
__global__ void ea_mean_kernel(const float* __restrict__ ea, float* acc, int E) {
  float a[16];
#pragma unroll
  for (int i = 0; i < 16; ++i) a[i] = 0.f;
  int stride = gridDim.x * blockDim.x;
  for (int e = blockIdx.x * blockDim.x + threadIdx.x; e < E; e += stride) {
    const float4* p = (const float4*)(ea + (size_t)e * 16);
    float4 x0 = p[0], x1 = p[1], x2 = p[2], x3 = p[3];
    a[0] += x0.x;  a[1] += x0.y;  a[2] += x0.z;  a[3] += x0.w;
    a[4] += x1.x;  a[5] += x1.y;  a[6] += x1.z;  a[7] += x1.w;
    a[8] += x2.x;  a[9] += x2.y;  a[10] += x2.z; a[11] += x2.w;
    a[12] += x3.x; a[13] += x3.y; a[14] += x3.z; a[15] += x3.w;
  }
  __shared__ float s[16];
  if (threadIdx.x < 16) s[threadIdx.x] = 0.f;
  __syncthreads();
#pragma unroll
  for (int i = 0; i < 16; ++i) atomicAdd(&s[i], a[i]);
  __syncthreads();
  if (threadIdx.x < 16) atomicAdd(&acc[threadIdx.x], s[threadIdx.x]);
}

// ---------- per-layer: le[e,h] = (ea @ We) . aE  ==  ea @ wered[16,4] ----------
__global__ void le_kernel(const float* __restrict__ ea, const float* __restrict__ We,
                          const float* __restrict__ aE, float* __restrict__ le, int E) {
  __shared__ float wr[16][4];
  int t = threadIdx.x;
  if (t < 64) {
    int f = t >> 2, h = t & 3;
    float s = 0.f;
    for (int c = 0; c < 32; ++c) s += We[f * 128 + h * 32 + c] * aE[h * 32 + c];
    wr[f][h] = s;
  }
  __syncthreads();
  int stride = gridDim.x * blockDim.x;
  for (int e = blockIdx.x * blockDim.x + t; e < E; e += stride) {
    const float4* p = (const float4*)(ea + (size_t)e * 16);
    float4 x0 = p[0], x1 = p[1], x2 = p[2], x3 = p[3];
    float xf[16] = {x0.x, x0.y, x0.z, x0.w, x1.x, x1.y, x1.z, x1.w,
                    x2.x, x2.y, x2.z, x2.w, x3.x, x3.y, x3.z, x3.w};
    float oo[4];
#pragma unroll
    for (int h = 0; h < 4; ++h) {
      float s = 0.f;
#pragma unroll
      for (int f = 0; f < 16; ++f) s += xf[f] * wr[f][h];
      oo[h] = s;
    }
    *(float4*)(le + (size_t)e * 4) = make_float4(oo[0], oo[1], oo[2], oo[3]);
  }
}

__global__ void le_self_kernel(const float* __restrict__ mean_acc, float scale,
                               const float* __restrict__ We, const float* __restrict__ aE,
                               float* __restrict__ le, int E) {
  __shared__ float wr[16][4];
  int t = threadIdx.x;
  if (t < 64) {
    int f = t >> 2, h = t & 3;
    float s = 0.f;
    for (int c = 0; c < 32; ++c) s += We[f * 128 + h * 32 + c] * aE[h * 32 + c];
    wr[f][h] = s;
  }
  __syncthreads();
  if (t < 4) {
    float s = 0.f;
    for (int f = 0; f < 16; ++f) s += mean_acc[f] * scale * wr[f][t];
    le[(size_t)E * 4 + t] = s;
  }
}

// ---------- node projection GEMM + fused alpha_src/alpha_dst ----------
template <int K>
__global__ __launch_bounds__(128) void proj_kernel(
    const float* __restrict__ in, const float* __restrict__ W,
    const float* __restrict__ aS, const float* __restrict__ aD,
    float* __restrict__ hp, float* __restrict__ ls, float* __restrict__ ldv, int n) {
  __shared__ float xs[8][K];
  int t = threadIdx.x;
  int base = blockIdx.x * 8;
  for (int idx = t; idx < 8 * K; idx += 128) {
    int r = idx / K, k = idx - r * K;
    int row = base + r;
    xs[r][k] = (row < n) ? in[(size_t)row * K + k] : 0.f;
  }
  __syncthreads();
  float acc[8];
#pragma unroll
  for (int r = 0; r < 8; ++r) acc[r] = 0.f;
  for (int k = 0; k < K; ++k) {
    float w = W[k * 128 + t];
#pragma unroll
    for (int r = 0; r < 8; ++r) acc[r] += xs[r][k] * w;
  }
  float sA = aS[t], sD = aD[t];
  int h = t >> 5;
#pragma unroll
  for (int r = 0; r < 8; ++r) {
    int row = base + r;
    if (row < n) hp[(size_t)row * 128 + t] = acc[r];
    float vS = acc[r] * sA;
    float vD = acc[r] * sD;
#pragma unroll
    for (int off = 1; off < 32; off <<= 1) {
      vS += __shfl_xor(vS, off);
      vD += __shfl_xor(vD, off);
    }
    if ((t & 31) == 0 && row < n) {
      ls[(size_t)row * 4 + h] = vS;
      ldv[(size_t)row * 4 + h] = vD;
    }
  }
}

// ---------- wave-per-node softmax + gather-aggregate ----------
__global__ __launch_bounds__(256) void agg_kernel(
    const float* __restrict__ hp, const float* __restrict__ ls,
    const float* __restrict__ ldv, const float* __restrict__ le,
    const int* __restrict__ rowptr, const int* __restrict__ esrc,
    const int* __restrict__ eeid, const float* __restrict__ bias,
    float* __restrict__ out, int n, int do_elu) {
  int wid = (blockIdx.x * blockDim.x + threadIdx.x) >> 6;
  int lane = threadIdx.x & 63;
  if (wid >= n) return;
  int lo = rowptr[wid], hi = rowptr[wid + 1];
  float4 ldn = *(const float4*)(ldv + (size_t)wid * 4);

  // pass 1a: segment max per head
  float m0 = -1e30f, m1 = -1e30f, m2 = -1e30f, m3 = -1e30f;
  for (int e = lo + lane; e < hi; e += 64) {
    int src = esrc[e];
    int id = eeid[e];
    float4 lsv = *(const float4*)(ls + (size_t)src * 4);
    float4 lev = *(const float4*)(le + (size_t)id * 4);
    float g0 = lsv.x + ldn.x + lev.x; g0 = g0 > 0.f ? g0 : 0.2f * g0;
    float g1 = lsv.y + ldn.y + lev.y; g1 = g1 > 0.f ? g1 : 0.2f * g1;
    float g2 = lsv.z + ldn.z + lev.z; g2 = g2 > 0.f ? g2 : 0.2f * g2;
    float g3 = lsv.w + ldn.w + lev.w; g3 = g3 > 0.f ? g3 : 0.2f * g3;
    m0 = fmaxf(m0, g0); m1 = fmaxf(m1, g1); m2 = fmaxf(m2, g2); m3 = fmaxf(m3, g3);
  }
#pragma unroll
  for (int off = 1; off < 64; off <<= 1) {
    m0 = fmaxf(m0, __shfl_xor(m0, off));
    m1 = fmaxf(m1, __shfl_xor(m1, off));
    m2 = fmaxf(m2, __shfl_xor(m2, off));
    m3 = fmaxf(m3, __shfl_xor(m3, off));
  }
  if (m0 < -1e29f) m0 = 0.f;
  if (m1 < -1e29f) m1 = 0.f;
  if (m2 < -1e29f) m2 = 0.f;
  if (m3 < -1e29f) m3 = 0.f;

  // pass 1b: segment sum of exp
  float s0 = 0.f, s1 = 0.f, s2 = 0.f, s3 = 0.f;
  for (int e = lo + lane; e < hi; e += 64) {
    int src = esrc[e];
    int id = eeid[e];
    float4 lsv = *(const float4*)(ls + (size_t)src * 4);
    float4 lev = *(const float4*)(le + (size_t)id * 4);
    float g0 = lsv.x + ldn.x + lev.x; g0 = g0 > 0.f ? g0 : 0.2f * g0;
    float g1 = lsv.y + ldn.y + lev.y; g1 = g1 > 0.f ? g1 : 0.2f * g1;
    float g2 = lsv.z + ldn.z + lev.z; g2 = g2 > 0.f ? g2 : 0.2f * g2;
    float g3 = lsv.w + ldn.w + lev.w; g3 = g3 > 0.f ? g3 : 0.2f * g3;
    s0 += __expf(g0 - m0); s1 += __expf(g1 - m1);
    s2 += __expf(g2 - m2); s3 += __expf(g3 - m3);
  }
#pragma unroll
  for (int off = 1; off < 64; off <<= 1) {
    s0 += __shfl_xor(s0, off);
    s1 += __shfl_xor(s1, off);
    s2 += __shfl_xor(s2, off);
    s3 += __shfl_xor(s3, off);
  }
  s0 += 1e-16f; s1 += 1e-16f; s2 += 1e-16f; s3 += 1e-16f;

  // pass 2: gather hp[src] rows weighted by alpha
  int h = lane >> 4;         // lane covers cols [2*lane, 2*lane+1], head = col>>5
  int col = lane * 2;
  float mh = h == 0 ? m0 : (h == 1 ? m1 : (h == 2 ? m2 : m3));
  float dh = h == 0 ? s0 : (h == 1 ? s1 : (h == 2 ? s2 : s3));
  float ldh = h == 0 ? ldn.x : (h == 1 ? ldn.y : (h == 2 ? ldn.z : ldn.w));
  float a0 = 0.f, a1 = 0.f;
  for (int e = lo; e < hi; ++e) {
    int src = esrc[e];
    int id = eeid[e];
    float g = ls[(size_t)src * 4 + h] + ldh + le[(size_t)id * 4 + h];
    g = g > 0.f ? g : 0.2f * g;
    float alpha = __expf(g - mh) / dh;
    float2 v = *(const float2*)(hp + (size_t)src * 128 + col);
    a0 += alpha * v.x;
    a1 += alpha * v.y;
  }
  float o0 = a0 + bias[col];
  float o1 = a1 + bias[col + 1];
  if (do_elu) {
    o0 = o0 > 0.f ? o0 : expm1f(o0);
    o1 = o1 > 0.f ? o1 : expm1f(o1);
  }
  *(float2*)(out + (size_t)wid * 128 + col) = make_float2(o0, o1);
}

// ---------- loc head: relu(h@Wl1+bl1)@Wl2+bl2, wave per node ----------
__global__ __launch_bounds__(256) void loc_kernel(
    const float* __restrict__ h, const float* __restrict__ Wl1,
    const float* __restrict__ bl1, const float* __restrict__ Wl2,
    const float* __restrict__ bl2, float* __restrict__ out, int n) {
  int wid = (blockIdx.x * blockDim.x + threadIdx.x) >> 6;
  int lane = threadIdx.x & 63;
  if (wid >= n) return;
  const float* hr = h + (size_t)wid * 128;
  float acc = bl1[lane];
  for (int k = 0; k < 128; k += 4) {
    float4 hv = *(const float4*)(hr + k);
    acc += hv.x * Wl1[(k + 0) * 64 + lane];
    acc += hv.y * Wl1[(k + 1) * 64 + lane];
    acc += hv.z * Wl1[(k + 2) * 64 + lane];
    acc += hv.w * Wl1[(k + 3) * 64 + lane];
  }
  acc = fmaxf(acc, 0.f) * Wl2[lane];
#pragma unroll
  for (int off = 1; off < 64; off <<= 1) acc += __shfl_xor(acc, off);
  if (lane == 0) out[wid] = acc + bl2[0];
}

// ---------- class head: segment-mean pool (batch sorted) + 2-layer MLP ----------
__global__ __launch_bounds__(128) void class_kernel(
    const float* __restrict__ h, const int* __restrict__ batch,
    const float* __restrict__ Wc1, const float* __restrict__ bc1,
    const float* __restrict__ Wc2, const float* __restrict__ bc2,
    float* __restrict__ out, int n) {
  int g = blockIdx.x;
  int t = threadIdx.x;
  int lo = 0, hi = n;
  while (lo < hi) { int mid = (lo + hi) >> 1; if (batch[mid] < g) lo = mid + 1; else hi = mid; }
  int a = lo, b2 = n;
  while (a < b2) { int mid = (a + b2) >> 1; if (batch[mid] < g + 1) a = mid + 1; else b2 = mid; }
  int s = lo, e2 = a;
  float acc = 0.f;
  for (int r = s; r < e2; ++r) acc += h[(size_t)r * 128 + t];
  int cnt = e2 - s;
  float denom = cnt > 0 ? (float)cnt : 1.f;
  __shared__ float gemb[128];
  __shared__ float hidl[128];
  gemb[t] = acc / denom;
  __syncthreads();
  float hid = bc1[t];
  for (int k = 0; k < 128; ++k) hid += gemb[k] * Wc1[k * 128 + t];
  hidl[t] = fmaxf(hid, 0.f);
  __syncthreads();
  if (t < 10) {
    float o = bc2[t];
    for (int k = 0; k < 128; ++k) o += hidl[k] * Wc2[k * 10 + t];
    out[g * 10 + t] = o;
  }
}

extern "C" void kernel_launch(void* const* d_in, const int* in_sizes, int n_in,
                              void* d_out, int out_size, void* d_ws, size_t ws_size,
                              hipStream_t stream) {
  const float* x = (const float*)d_in[0];
  const int* ei = (const int*)d_in[1];
  const float* ea = (const float*)d_in[2];
  const int* batch = (const int*)d_in[3];
  const float* W[3]  = {(const float*)d_in[4],  (const float*)d_in[10], (const float*)d_in[16]};
  const float* aS[3] = {(const float*)d_in[5],  (const float*)d_in[11], (const float*)d_in[17]};
  const float* aD[3] = {(const float*)d_in[6],  (const float*)d_in[12], (const float*)d_in[18]};
  const float* We[3] = {(const float*)d_in[7],  (const float*)d_in[13], (const float*)d_in[19]};
  const float* aE[3] = {(const float*)d_in[8],  (const float*)d_in[14], (const float*)d_in[20]};
  const float* bb[3] = {(const float*)d_in[9],  (const float*)d_in[15], (const float*)d_in[21]};
  const float* Wc1 = (const float*)d_in[22];
  const float* bc1 = (const float*)d_in[23];
  const float* Wc2 = (const float*)d_in[24];
  const float* bc2 = (const float*)d_in[25];
  const float* Wl1 = (const float*)d_in[26];
  const float* bl1 = (const float*)d_in[27];
  const float* Wl2 = (const float*)d_in[28];
  const float* bl2 = (const float*)d_in[29];

  const int N = in_sizes[0] / 64;
  const int E = in_sizes[1] / 2;
  const int EP = E + N;

  char* p = (char*)d_ws;
  auto alloc = [&](size_t bytes) {
    char* r = p;
    p += (bytes + 255) & ~(size_t)255;
    return r;
  };
  float* A      = (float*)alloc((size_t)N * 128 * 4);  // layer io
  float* hp     = (float*)alloc((size_t)N * 128 * 4);  // projected features
  float* ls     = (float*)alloc((size_t)N * 4 * 4);
  float* ldv    = (float*)alloc((size_t)N * 4 * 4);
  float* le     = (float*)alloc((size_t)(E + 1) * 4 * 4);  // row E = self-loop le
  int* rowptr   = (int*)alloc((size_t)(N + 1) * 4);
  int* cursor   = (int*)alloc((size_t)N * 4);  // doubles as degree count
  int* bsum     = (int*)alloc(256 * 4);
  int* esrc     = (int*)alloc((size_t)EP * 4);
  int* eeid     = (int*)alloc((size_t)EP * 4);
  float* m_acc  = (float*)alloc(16 * 4);

  float* out_cls = (float*)d_out;
  float* out_loc = (float*)d_out + 640;

  int nb = (N + SCAN_TILE - 1) / SCAN_TILE;

  init_cnt_kernel<<<(N + 255) / 256, 256, 0, stream>>>(cursor, m_acc, N);
  count_kernel<<<1024, 256, 0, stream>>>(ei + E, cursor, E);
  scan1_kernel<<<nb, 256, 0, stream>>>(cursor, rowptr, bsum, N);
  scan2_kernel<<<1, 64, 0, stream>>>(bsum, nb, rowptr);
  scan3_kernel<<<nb, 256, 0, stream>>>(bsum, rowptr, N);
  copy_cursor_kernel<<<(N + 255) / 256, 256, 0, stream>>>(rowptr, cursor, N);
  ea_mean_kernel<<<512, 256, 0, stream>>>(ea, m_acc, E);
  scatter_kernel<<<2048, 256, 0, stream>>>(ei, cursor, esrc, eeid, E, N);

  for (int l = 0; l < 3; ++l) {
    le_kernel<<<2048, 256, 0, stream>>>(ea, We[l], aE[l], le, E);
    le_self_kernel<<<1, 64, 0, stream>>>(m_acc, 1.0f / (float)E, We[l], aE[l], le, E);
    if (l == 0)
      proj_kernel<64><<<(N + 7) / 8, 128, 0, stream>>>(x, W[0], aS[0], aD[0], hp, ls, ldv, N);
    else
      proj_kernel<128><<<(N + 7) / 8, 128, 0, stream>>>(A, W[l], aS[l], aD[l], hp, ls, ldv, N);
    agg_kernel<<<(N * 64 + 255) / 256, 256, 0, stream>>>(
        hp, ls, ldv, le, rowptr, esrc, eeid, bb[l], A, N, l < 2 ? 1 : 0);
  }

  loc_kernel<<<(N * 64 + 255) / 256, 256, 0, stream>>>(A, Wl1, bl1, Wl2, bl2, out_loc, N);
  class_kernel<<<64, 128, 0, stream>>>(A, batch, Wc1, bc1, Wc2, bc2, out_cls, N);
}

// Round 3
// 1678.665 us; speedup vs baseline: 1.2181x; 1.2181x over previous
//
#include <hip/hip_runtime.h>
#include <math.h>

// GridGNN: 3x GATConv(H=4,C=32,concat) + ELU between, then node-level MLP head
// (loc_logits) and graph-pool MLP head (class_logits).
// Strategy: build CSR by dst once (counting sort), wave-per-node online-softmax
// + gather. Class head: parallel segment pool (atomic flush) + tiny MLP.

constexpr int SCAN_TILE = 2048;  // 256 threads * 8 elements

// ---------- CSR build ----------
__global__ void init_cnt_kernel(int* cnt, float* mean_acc, int n) {
  int i = blockIdx.x * blockDim.x + threadIdx.x;
  if (i < n) cnt[i] = 1;  // every node gets one self-loop
  if (blockIdx.x == 0 && threadIdx.x < 16) mean_acc[threadIdx.x] = 0.f;
}

__global__ void count_kernel(const int* __restrict__ dst, int* cnt, int E) {
  int stride = gridDim.x * blockDim.x;
  for (int e = blockIdx.x * blockDim.x + threadIdx.x; e < E; e += stride)
    atomicAdd(&cnt[dst[e]], 1);
}

__global__ void scan1_kernel(const int* __restrict__ cnt, int* rowptr, int* bsum, int n) {
  __shared__ int part[256];
  int t = threadIdx.x, b = blockIdx.x;
  int base = b * SCAN_TILE + t * 8;
  int v[8];
  int s = 0;
#pragma unroll
  for (int i = 0; i < 8; ++i) {
    int idx = base + i;
    v[i] = (idx < n) ? cnt[idx] : 0;
    s += v[i];
  }
  part[t] = s;
  __syncthreads();
  if (t == 0) {
    int run = 0;
    for (int i = 0; i < 256; ++i) { int x = part[i]; part[i] = run; run += x; }
    bsum[b] = run;
  }
  __syncthreads();
  int run = part[t];
#pragma unroll
  for (int i = 0; i < 8; ++i) {
    int idx = base + i;
    run += v[i];
    if (idx < n) rowptr[idx + 1] = run;
  }
}

__global__ void scan2_kernel(int* bsum, int nb, int* rowptr) {
  if (threadIdx.x == 0 && blockIdx.x == 0) {
    rowptr[0] = 0;
    int run = 0;
    for (int b = 0; b < nb; ++b) { int x = bsum[b]; bsum[b] = run; run += x; }
  }
}

__global__ void scan3_kernel(const int* __restrict__ bsum, int* rowptr, int n) {
  int off = bsum[blockIdx.x];
  int base = blockIdx.x * SCAN_TILE + threadIdx.x * 8;
#pragma unroll
  for (int i = 0; i < 8; ++i) {
    int idx = base + i;
    if (idx < n) rowptr[idx + 1] += off;
  }
}

__global__ void copy_cursor_kernel(const int* __restrict__ rowptr, int* cursor, int n) {
  int i = blockIdx.x * blockDim.x + threadIdx.x;
  if (i < n) cursor[i] = rowptr[i];
}

__global__ void scatter_kernel(const int* __restrict__ ei, int* cursor,
                               int* esrc, int* eeid, int E, int n) {
  int stride = gridDim.x * blockDim.x;
  int total = E + n;
  for (int i = blockIdx.x * blockDim.x + threadIdx.x; i < total; i += stride) {
    int s, d, id;
    if (i < E) { s = ei[i]; d = ei[E + i]; id = i; }
    else       { s = i - E; d = s; id = E; }  // self loop; le row E = self le
    int pos = atomicAdd(&cursor[d], 1);
    esrc[pos] = s;
    eeid[pos] = id;
  }
}

// ---------- per-layer: le[e,h] = (ea @ We) . aE  ==  ea @ wered[16,4] ----------
// MEAN variant additionally accumulates column sums of ea into m_acc (for the
// self-loop fill value), saving a separate full pass over edge_attr.
template <bool MEAN>
__global__ void le_kernel(const float* __restrict__ ea, const float* __restrict__ We,
                          const float* __restrict__ aE, float* __restrict__ le,
                          float* __restrict__ m_acc, int E) {
  __shared__ float wr[16][4];
  int t = threadIdx.x;
  if (t < 64) {
    int f = t >> 2, h = t & 3;
    float s = 0.f;
    for (int c = 0; c < 32; ++c) s += We[f * 128 + h * 32 + c] * aE[h * 32 + c];
    wr[f][h] = s;
  }
  __syncthreads();
  float a[16];
  if (MEAN) {
#pragma unroll
    for (int i = 0; i < 16; ++i) a[i] = 0.f;
  }
  int stride = gridDim.x * blockDim.x;
  for (int e = blockIdx.x * blockDim.x + t; e < E; e += stride) {
    const float4* p = (const float4*)(ea + (size_t)e * 16);
    float4 x0 = p[0], x1 = p[1], x2 = p[2], x3 = p[3];
    float xf[16] = {x0.x, x0.y, x0.z, x0.w, x1.x, x1.y, x1.z, x1.w,
                    x2.x, x2.y, x2.z, x2.w, x3.x, x3.y, x3.z, x3.w};
    if (MEAN) {
#pragma unroll
      for (int i = 0; i < 16; ++i) a[i] += xf[i];
    }
    float oo[4];
#pragma unroll
    for (int h = 0; h < 4; ++h) {
      float s = 0.f;
#pragma unroll
      for (int f = 0; f < 16; ++f) s += xf[f] * wr[f][h];
      oo[h] = s;
    }
    *(float4*)(le + (size_t)e * 4) = make_float4(oo[0], oo[1], oo[2], oo[3]);
  }
  if (MEAN) {
    __shared__ float sm[16];
    if (t < 16) sm[t] = 0.f;
    __syncthreads();
#pragma unroll
    for (int i = 0; i < 16; ++i) atomicAdd(&sm[i], a[i]);
    __syncthreads();
    if (t < 16) atomicAdd(&m_acc[t], sm[t]);
  }
}

__global__ void le_self_kernel(const float* __restrict__ mean_acc, float scale,
                               const float* __restrict__ We, const float* __restrict__ aE,
                               float* __restrict__ le, int E) {
  __shared__ float wr[16][4];
  int t = threadIdx.x;
  if (t < 64) {
    int f = t >> 2, h = t & 3;
    float s = 0.f;
    for (int c = 0; c < 32; ++c) s += We[f * 128 + h * 32 + c] * aE[h * 32 + c];
    wr[f][h] = s;
  }
  __syncthreads();
  if (t < 4) {
    float s = 0.f;
    for (int f = 0; f < 16; ++f) s += mean_acc[f] * scale * wr[f][t];
    le[(size_t)E * 4 + t] = s;
  }
}

// ---------- node projection GEMM + fused alpha_src/alpha_dst ----------
template <int K>
__global__ __launch_bounds__(128) void proj_kernel(
    const float* __restrict__ in, const float* __restrict__ W,
    const float* __restrict__ aS, const float* __restrict__ aD,
    float* __restrict__ hp, float* __restrict__ ls, float* __restrict__ ldv, int n) {
  __shared__ float xs[8][K];
  int t = threadIdx.x;
  int base = blockIdx.x * 8;
  for (int idx = t; idx < 8 * K; idx += 128) {
    int r = idx / K, k = idx - r * K;
    int row = base + r;
    xs[r][k] = (row < n) ? in[(size_t)row * K + k] : 0.f;
  }
  __syncthreads();
  float acc[8];
#pragma unroll
  for (int r = 0; r < 8; ++r) acc[r] = 0.f;
  for (int k = 0; k < K; ++k) {
    float w = W[k * 128 + t];
#pragma unroll
    for (int r = 0; r < 8; ++r) acc[r] += xs[r][k] * w;
  }
  float sA = aS[t], sD = aD[t];
  int h = t >> 5;
#pragma unroll
  for (int r = 0; r < 8; ++r) {
    int row = base + r;
    if (row < n) hp[(size_t)row * 128 + t] = acc[r];
    float vS = acc[r] * sA;
    float vD = acc[r] * sD;
#pragma unroll
    for (int off = 1; off < 32; off <<= 1) {
      vS += __shfl_xor(vS, off);
      vD += __shfl_xor(vD, off);
    }
    if ((t & 31) == 0 && row < n) {
      ls[(size_t)row * 4 + h] = vS;
      ldv[(size_t)row * 4 + h] = vD;
    }
  }
}

// ---------- wave-per-node online softmax + gather-aggregate ----------
__global__ __launch_bounds__(256) void agg_kernel(
    const float* __restrict__ hp, const float* __restrict__ ls,
    const float* __restrict__ ldv, const float* __restrict__ le,
    const int* __restrict__ rowptr, const int* __restrict__ esrc,
    const int* __restrict__ eeid, const float* __restrict__ bias,
    float* __restrict__ out, int n, int do_elu) {
  int wid = (blockIdx.x * blockDim.x + threadIdx.x) >> 6;
  int lane = threadIdx.x & 63;
  if (wid >= n) return;
  int lo = rowptr[wid], hi = rowptr[wid + 1];
  float4 ldn = *(const float4*)(ldv + (size_t)wid * 4);

  // pass 1: online softmax (running max + rescaled sum) per head, per lane
  float m0 = -1e30f, m1 = -1e30f, m2 = -1e30f, m3 = -1e30f;
  float s0 = 0.f, s1 = 0.f, s2 = 0.f, s3 = 0.f;
  for (int e = lo + lane; e < hi; e += 64) {
    int src = esrc[e];
    int id = eeid[e];
    float4 lsv = *(const float4*)(ls + (size_t)src * 4);
    float4 lev = *(const float4*)(le + (size_t)id * 4);
    float g0 = lsv.x + ldn.x + lev.x; g0 = g0 > 0.f ? g0 : 0.2f * g0;
    float g1 = lsv.y + ldn.y + lev.y; g1 = g1 > 0.f ? g1 : 0.2f * g1;
    float g2 = lsv.z + ldn.z + lev.z; g2 = g2 > 0.f ? g2 : 0.2f * g2;
    float g3 = lsv.w + ldn.w + lev.w; g3 = g3 > 0.f ? g3 : 0.2f * g3;
    float nm;
    nm = fmaxf(m0, g0); s0 = s0 * __expf(m0 - nm) + __expf(g0 - nm); m0 = nm;
    nm = fmaxf(m1, g1); s1 = s1 * __expf(m1 - nm) + __expf(g1 - nm); m1 = nm;
    nm = fmaxf(m2, g2); s2 = s2 * __expf(m2 - nm) + __expf(g2 - nm); m2 = nm;
    nm = fmaxf(m3, g3); s3 = s3 * __expf(m3 - nm) + __expf(g3 - nm); m3 = nm;
  }
  // merge (m,s) across the 64 lanes
#pragma unroll
  for (int off = 1; off < 64; off <<= 1) {
    float om, os, nm;
    om = __shfl_xor(m0, off); os = __shfl_xor(s0, off);
    nm = fmaxf(m0, om); s0 = s0 * __expf(m0 - nm) + os * __expf(om - nm); m0 = nm;
    om = __shfl_xor(m1, off); os = __shfl_xor(s1, off);
    nm = fmaxf(m1, om); s1 = s1 * __expf(m1 - nm) + os * __expf(om - nm); m1 = nm;
    om = __shfl_xor(m2, off); os = __shfl_xor(s2, off);
    nm = fmaxf(m2, om); s2 = s2 * __expf(m2 - nm) + os * __expf(om - nm); m2 = nm;
    om = __shfl_xor(m3, off); os = __shfl_xor(s3, off);
    nm = fmaxf(m3, om); s3 = s3 * __expf(m3 - nm) + os * __expf(om - nm); m3 = nm;
  }
  if (m0 < -1e29f) m0 = 0.f;
  if (m1 < -1e29f) m1 = 0.f;
  if (m2 < -1e29f) m2 = 0.f;
  if (m3 < -1e29f) m3 = 0.f;
  s0 += 1e-16f; s1 += 1e-16f; s2 += 1e-16f; s3 += 1e-16f;

  // pass 2: gather hp[src] rows weighted by alpha
  int h = lane >> 4;         // lane covers cols [2*lane, 2*lane+1], head = col>>5
  int col = lane * 2;
  float mh = h == 0 ? m0 : (h == 1 ? m1 : (h == 2 ? m2 : m3));
  float rdh = 1.0f / (h == 0 ? s0 : (h == 1 ? s1 : (h == 2 ? s2 : s3)));
  float ldh = h == 0 ? ldn.x : (h == 1 ? ldn.y : (h == 2 ? ldn.z : ldn.w));
  float a0 = 0.f, a1 = 0.f;
  for (int e = lo; e < hi; ++e) {
    int src = esrc[e];
    int id = eeid[e];
    float g = ls[(size_t)src * 4 + h] + ldh + le[(size_t)id * 4 + h];
    g = g > 0.f ? g : 0.2f * g;
    float alpha = __expf(g - mh) * rdh;
    float2 v = *(const float2*)(hp + (size_t)src * 128 + col);
    a0 += alpha * v.x;
    a1 += alpha * v.y;
  }
  float o0 = a0 + bias[col];
  float o1 = a1 + bias[col + 1];
  if (do_elu) {
    o0 = o0 > 0.f ? o0 : expm1f(o0);
    o1 = o1 > 0.f ? o1 : expm1f(o1);
  }
  *(float2*)(out + (size_t)wid * 128 + col) = make_float2(o0, o1);
}

// ---------- loc head: relu(h@Wl1+bl1)@Wl2+bl2, wave per node ----------
__global__ __launch_bounds__(256) void loc_kernel(
    const float* __restrict__ h, const float* __restrict__ Wl1,
    const float* __restrict__ bl1, const float* __restrict__ Wl2,
    const float* __restrict__ bl2, float* __restrict__ out, int n) {
  int wid = (blockIdx.x * blockDim.x + threadIdx.x) >> 6;
  int lane = threadIdx.x & 63;
  if (wid >= n) return;
  const float* hr = h + (size_t)wid * 128;
  float acc = bl1[lane];
  for (int k = 0; k < 128; k += 4) {
    float4 hv = *(const float4*)(hr + k);
    acc += hv.x * Wl1[(k + 0) * 64 + lane];
    acc += hv.y * Wl1[(k + 1) * 64 + lane];
    acc += hv.z * Wl1[(k + 2) * 64 + lane];
    acc += hv.w * Wl1[(k + 3) * 64 + lane];
  }
  acc = fmaxf(acc, 0.f) * Wl2[lane];
#pragma unroll
  for (int off = 1; off < 64; off <<= 1) acc += __shfl_xor(acc, off);
  if (lane == 0) out[wid] = acc + bl2[0];
}

// ---------- class head: zero -> parallel segment-sum pool -> tiny MLP ----------
__global__ void zero_gemb_kernel(float* gemb) {
  int i = blockIdx.x * blockDim.x + threadIdx.x;
  if (i < 64 * 128) gemb[i] = 0.f;
}

// 128 threads (one per column); each block accumulates a 128-node slab of the
// sorted-batch node list in registers and flushes per group boundary.
__global__ __launch_bounds__(128) void pool_kernel(
    const float* __restrict__ h, const int* __restrict__ batch,
    float* __restrict__ gemb, int n) {
  int t = threadIdx.x;
  int base = blockIdx.x * 128;
  int end = base + 128 < n ? base + 128 : n;
  float acc = 0.f;
  int cur = -1;
  for (int node = base; node < end; ++node) {
    int g = batch[node];
    if (g != cur) {
      if (cur >= 0) atomicAdd(&gemb[cur * 128 + t], acc);
      acc = 0.f;
      cur = g;
    }
    acc += h[(size_t)node * 128 + t];
  }
  if (cur >= 0) atomicAdd(&gemb[cur * 128 + t], acc);
}

__global__ __launch_bounds__(128) void class_mlp_kernel(
    const float* __restrict__ gsum, const int* __restrict__ batch,
    const float* __restrict__ Wc1, const float* __restrict__ bc1,
    const float* __restrict__ Wc2, const float* __restrict__ bc2,
    float* __restrict__ out, int n) {
  int g = blockIdx.x;
  int t = threadIdx.x;
  // count nodes in group g via binary search (batch sorted)
  int lo = 0, hi = n;
  while (lo < hi) { int mid = (lo + hi) >> 1; if (batch[mid] < g) lo = mid + 1; else hi = mid; }
  int a = lo, b2 = n;
  while (a < b2) { int mid = (a + b2) >> 1; if (batch[mid] < g + 1) a = mid + 1; else b2 = mid; }
  int cnt = a - lo;
  float denom = cnt > 0 ? (float)cnt : 1.f;
  __shared__ float gemb[128];
  __shared__ float hidl[128];
  gemb[t] = gsum[g * 128 + t] / denom;
  __syncthreads();
  float hid = bc1[t];
  for (int k = 0; k < 128; ++k) hid += gemb[k] * Wc1[k * 128 + t];
  hidl[t] = fmaxf(hid, 0.f);
  __syncthreads();
  if (t < 10) {
    float o = bc2[t];
    for (int k = 0; k < 128; ++k) o += hidl[k] * Wc2[k * 10 + t];
    out[g * 10 + t] = o;
  }
}

extern "C" void kernel_launch(void* const* d_in, const int* in_sizes, int n_in,
                              void* d_out, int out_size, void* d_ws, size_t ws_size,
                              hipStream_t stream) {
  const float* x = (const float*)d_in[0];
  const int* ei = (const int*)d_in[1];
  const float* ea = (const float*)d_in[2];
  const int* batch = (const int*)d_in[3];
  const float* W[3]  = {(const float*)d_in[4],  (const float*)d_in[10], (const float*)d_in[16]};
  const float* aS[3] = {(const float*)d_in[5],  (const float*)d_in[11], (const float*)d_in[17]};
  const float* aD[3] = {(const float*)d_in[6],  (const float*)d_in[12], (const float*)d_in[18]};
  const float* We[3] = {(const float*)d_in[7],  (const float*)d_in[13], (const float*)d_in[19]};
  const float* aE[3] = {(const float*)d_in[8],  (const float*)d_in[14], (const float*)d_in[20]};
  const float* bb[3] = {(const float*)d_in[9],  (const float*)d_in[15], (const float*)d_in[21]};
  const float* Wc1 = (const float*)d_in[22];
  const float* bc1 = (const float*)d_in[23];
  const float* Wc2 = (const float*)d_in[24];
  const float* bc2 = (const float*)d_in[25];
  const float* Wl1 = (const float*)d_in[26];
  const float* bl1 = (const float*)d_in[27];
  const float* Wl2 = (const float*)d_in[28];
  const float* bl2 = (const float*)d_in[29];

  const int N = in_sizes[0] / 64;
  const int E = in_sizes[1] / 2;
  const int EP = E + N;

  char* p = (char*)d_ws;
  auto alloc = [&](size_t bytes) {
    char* r = p;
    p += (bytes + 255) & ~(size_t)255;
    return r;
  };
  float* A      = (float*)alloc((size_t)N * 128 * 4);  // layer io
  float* hp     = (float*)alloc((size_t)N * 128 * 4);  // projected features
  float* ls     = (float*)alloc((size_t)N * 4 * 4);
  float* ldv    = (float*)alloc((size_t)N * 4 * 4);
  float* le     = (float*)alloc((size_t)(E + 1) * 4 * 4);  // row E = self-loop le
  int* rowptr   = (int*)alloc((size_t)(N + 1) * 4);
  int* cursor   = (int*)alloc((size_t)N * 4);  // doubles as degree count
  int* bsum     = (int*)alloc(256 * 4);
  int* esrc     = (int*)alloc((size_t)EP * 4);
  int* eeid     = (int*)alloc((size_t)EP * 4);
  float* m_acc  = (float*)alloc(16 * 4);
  float* gemb   = (float*)alloc(64 * 128 * 4);

  float* out_cls = (float*)d_out;
  float* out_loc = (float*)d_out + 640;

  int nb = (N + SCAN_TILE - 1) / SCAN_TILE;

  init_cnt_kernel<<<(N + 255) / 256, 256, 0, stream>>>(cursor, m_acc, N);
  count_kernel<<<1024, 256, 0, stream>>>(ei + E, cursor, E);
  scan1_kernel<<<nb, 256, 0, stream>>>(cursor, rowptr, bsum, N);
  scan2_kernel<<<1, 64, 0, stream>>>(bsum, nb, rowptr);
  scan3_kernel<<<nb, 256, 0, stream>>>(bsum, rowptr, N);
  copy_cursor_kernel<<<(N + 255) / 256, 256, 0, stream>>>(rowptr, cursor, N);
  scatter_kernel<<<2048, 256, 0, stream>>>(ei, cursor, esrc, eeid, E, N);

  for (int l = 0; l < 3; ++l) {
    if (l == 0)
      le_kernel<true><<<2048, 256, 0, stream>>>(ea, We[0], aE[0], le, m_acc, E);
    else
      le_kernel<false><<<2048, 256, 0, stream>>>(ea, We[l], aE[l], le, nullptr, E);
    le_self_kernel<<<1, 64, 0, stream>>>(m_acc, 1.0f / (float)E, We[l], aE[l], le, E);
    if (l == 0)
      proj_kernel<64><<<(N + 7) / 8, 128, 0, stream>>>(x, W[0], aS[0], aD[0], hp, ls, ldv, N);
    else
      proj_kernel<128><<<(N + 7) / 8, 128, 0, stream>>>(A, W[l], aS[l], aD[l], hp, ls, ldv, N);
    agg_kernel<<<(N * 64 + 255) / 256, 256, 0, stream>>>(
        hp, ls, ldv, le, rowptr, esrc, eeid, bb[l], A, N, l < 2 ? 1 : 0);
  }

  loc_kernel<<<(N * 64 + 255) / 256, 256, 0, stream>>>(A, Wl1, bl1, Wl2, bl2, out_loc, N);
  zero_gemb_kernel<<<32, 256, 0, stream>>>(gemb);
  pool_kernel<<<(N + 127) / 128, 128, 0, stream>>>(A, batch, gemb, N);
  class_mlp_kernel<<<64, 128, 0, stream>>>(gemb, batch, Wc1, bc1, Wc2, bc2, out_cls, N);
}

// Round 4
// 1483.239 us; speedup vs baseline: 1.3786x; 1.1318x over previous
//
#include <hip/hip_runtime.h>
#include <math.h>

// GridGNN: 3x GATConv(H=4,C=32,concat) + ELU between, then node-level MLP head
// (loc_logits) and graph-pool MLP head (class_logits).
// Strategy: build CSR by dst once (counting sort); wave-per-node aggregation
// with LDS-cached logits (compute alpha once per edge-head, gather phase does
// only LDS-broadcast + coalesced hp row FMA). Class head: parallel segment
// pool (atomic flush) + tiny MLP.

constexpr int SCAN_TILE = 2048;  // 256 threads * 8 elements
constexpr int DEG_CAP = 128;     // LDS logit slab per wave; deg>CAP -> slow path

// ---------- CSR build ----------
__global__ void init_cnt_kernel(int* cnt, float* mean_acc, int n) {
  int i = blockIdx.x * blockDim.x + threadIdx.x;
  if (i < n) cnt[i] = 1;  // every node gets one self-loop
  if (blockIdx.x == 0 && threadIdx.x < 16) mean_acc[threadIdx.x] = 0.f;
}

__global__ void count_kernel(const int* __restrict__ dst, int* cnt, int E) {
  int stride = gridDim.x * blockDim.x;
  for (int e = blockIdx.x * blockDim.x + threadIdx.x; e < E; e += stride)
    atomicAdd(&cnt[dst[e]], 1);
}

__global__ void scan1_kernel(const int* __restrict__ cnt, int* rowptr, int* bsum, int n) {
  __shared__ int part[256];
  int t = threadIdx.x, b = blockIdx.x;
  int base = b * SCAN_TILE + t * 8;
  int v[8];
  int s = 0;
#pragma unroll
  for (int i = 0; i < 8; ++i) {
    int idx = base + i;
    v[i] = (idx < n) ? cnt[idx] : 0;
    s += v[i];
  }
  part[t] = s;
  __syncthreads();
  if (t == 0) {
    int run = 0;
    for (int i = 0; i < 256; ++i) { int x = part[i]; part[i] = run; run += x; }
    bsum[b] = run;
  }
  __syncthreads();
  int run = part[t];
#pragma unroll
  for (int i = 0; i < 8; ++i) {
    int idx = base + i;
    run += v[i];
    if (idx < n) rowptr[idx + 1] = run;
  }
}

__global__ void scan2_kernel(int* bsum, int nb, int* rowptr) {
  if (threadIdx.x == 0 && blockIdx.x == 0) {
    rowptr[0] = 0;
    int run = 0;
    for (int b = 0; b < nb; ++b) { int x = bsum[b]; bsum[b] = run; run += x; }
  }
}

// adds block offsets AND initializes the scatter cursor (fold of copy_cursor)
__global__ void scan3_kernel(const int* __restrict__ bsum, int* rowptr, int* cursor, int n) {
  int off = bsum[blockIdx.x];
  int base = blockIdx.x * SCAN_TILE + threadIdx.x * 8;
#pragma unroll
  for (int i = 0; i < 8; ++i) {
    int idx = base + i;
    if (idx < n) {
      int v = rowptr[idx + 1] + off;
      rowptr[idx + 1] = v;
      if (idx + 1 < n) cursor[idx + 1] = v;
    }
  }
  if (blockIdx.x == 0 && threadIdx.x == 0) cursor[0] = 0;
}

__global__ void scatter_kernel(const int* __restrict__ ei, int* cursor,
                               int* esrc, int* eeid, int E, int n) {
  int stride = gridDim.x * blockDim.x;
  int total = E + n;
  for (int i = blockIdx.x * blockDim.x + threadIdx.x; i < total; i += stride) {
    int s, d, id;
    if (i < E) { s = ei[i]; d = ei[E + i]; id = i; }
    else       { s = i - E; d = s; id = E; }  // self loop; le row E = self le
    int pos = atomicAdd(&cursor[d], 1);
    esrc[pos] = s;
    eeid[pos] = id;
  }
}

// ---------- per-layer: le[e,h] = (ea @ We) . aE  ==  ea @ wered[16,4] ----------
// MEAN variant additionally accumulates column sums of ea into m_acc (for the
// self-loop fill value), saving a separate full pass over edge_attr.
template <bool MEAN>
__global__ void le_kernel(const float* __restrict__ ea, const float* __restrict__ We,
                          const float* __restrict__ aE, float* __restrict__ le,
                          float* __restrict__ m_acc, int E) {
  __shared__ float wr[16][4];
  int t = threadIdx.x;
  if (t < 64) {
    int f = t >> 2, h = t & 3;
    float s = 0.f;
    for (int c = 0; c < 32; ++c) s += We[f * 128 + h * 32 + c] * aE[h * 32 + c];
    wr[f][h] = s;
  }
  __syncthreads();
  float a[16];
  if (MEAN) {
#pragma unroll
    for (int i = 0; i < 16; ++i) a[i] = 0.f;
  }
  int stride = gridDim.x * blockDim.x;
  for (int e = blockIdx.x * blockDim.x + t; e < E; e += stride) {
    const float4* p = (const float4*)(ea + (size_t)e * 16);
    float4 x0 = p[0], x1 = p[1], x2 = p[2], x3 = p[3];
    float xf[16] = {x0.x, x0.y, x0.z, x0.w, x1.x, x1.y, x1.z, x1.w,
                    x2.x, x2.y, x2.z, x2.w, x3.x, x3.y, x3.z, x3.w};
    if (MEAN) {
#pragma unroll
      for (int i = 0; i < 16; ++i) a[i] += xf[i];
    }
    float oo[4];
#pragma unroll
    for (int h = 0; h < 4; ++h) {
      float s = 0.f;
#pragma unroll
      for (int f = 0; f < 16; ++f) s += xf[f] * wr[f][h];
      oo[h] = s;
    }
    *(float4*)(le + (size_t)e * 4) = make_float4(oo[0], oo[1], oo[2], oo[3]);
  }
  if (MEAN) {
    __shared__ float sm[16];
    if (t < 16) sm[t] = 0.f;
    __syncthreads();
#pragma unroll
    for (int i = 0; i < 16; ++i) atomicAdd(&sm[i], a[i]);
    __syncthreads();
    if (t < 16) atomicAdd(&m_acc[t], sm[t]);
  }
}

__global__ void le_self_kernel(const float* __restrict__ mean_acc, float scale,
                               const float* __restrict__ We, const float* __restrict__ aE,
                               float* __restrict__ le, int E) {
  __shared__ float wr[16][4];
  int t = threadIdx.x;
  if (t < 64) {
    int f = t >> 2, h = t & 3;
    float s = 0.f;
    for (int c = 0; c < 32; ++c) s += We[f * 128 + h * 32 + c] * aE[h * 32 + c];
    wr[f][h] = s;
  }
  __syncthreads();
  if (t < 4) {
    float s = 0.f;
    for (int f = 0; f < 16; ++f) s += mean_acc[f] * scale * wr[f][t];
    le[(size_t)E * 4 + t] = s;
  }
}

// ---------- node projection GEMM + fused alpha_src/alpha_dst ----------
template <int K>
__global__ __launch_bounds__(128) void proj_kernel(
    const float* __restrict__ in, const float* __restrict__ W,
    const float* __restrict__ aS, const float* __restrict__ aD,
    float* __restrict__ hp, float* __restrict__ ls, float* __restrict__ ldv, int n) {
  __shared__ float xs[8][K];
  int t = threadIdx.x;
  int base = blockIdx.x * 8;
  for (int idx = t; idx < 8 * K; idx += 128) {
    int r = idx / K, k = idx - r * K;
    int row = base + r;
    xs[r][k] = (row < n) ? in[(size_t)row * K + k] : 0.f;
  }
  __syncthreads();
  float acc[8];
#pragma unroll
  for (int r = 0; r < 8; ++r) acc[r] = 0.f;
  for (int k = 0; k < K; ++k) {
    float w = W[k * 128 + t];
#pragma unroll
    for (int r = 0; r < 8; ++r) acc[r] += xs[r][k] * w;
  }
  float sA = aS[t], sD = aD[t];
  int h = t >> 5;
#pragma unroll
  for (int r = 0; r < 8; ++r) {
    int row = base + r;
    if (row < n) hp[(size_t)row * 128 + t] = acc[r];
    float vS = acc[r] * sA;
    float vD = acc[r] * sD;
#pragma unroll
    for (int off = 1; off < 32; off <<= 1) {
      vS += __shfl_xor(vS, off);
      vD += __shfl_xor(vD, off);
    }
    if ((t & 31) == 0 && row < n) {
      ls[(size_t)row * 4 + h] = vS;
      ldv[(size_t)row * 4 + h] = vD;
    }
  }
}

// ---------- wave-per-node aggregation with LDS-cached logits ----------
__global__ __launch_bounds__(256) void agg_kernel(
    const float* __restrict__ hp, const float* __restrict__ ls,
    const float* __restrict__ ldv, const float* __restrict__ le,
    const int* __restrict__ rowptr, const int* __restrict__ esrc,
    const int* __restrict__ eeid, const float* __restrict__ bias,
    float* __restrict__ out, int n, int do_elu) {
  __shared__ float gall[4][DEG_CAP * 4];  // per-wave logit/alpha slab (8 KB)
  float* gl = gall[threadIdx.x >> 6];
  int wid = (blockIdx.x * blockDim.x + threadIdx.x) >> 6;
  int lane = threadIdx.x & 63;
  if (wid >= n) return;
  int lo = rowptr[wid], hi = rowptr[wid + 1];
  int deg = hi - lo;
  float4 ldn = *(const float4*)(ldv + (size_t)wid * 4);
  int h = lane >> 4;  // head for gather phase: lane covers cols [2*lane,2*lane+1]
  int col = lane * 2;
  float ldh = h == 0 ? ldn.x : (h == 1 ? ldn.y : (h == 2 ? ldn.z : ldn.w));
  float a0 = 0.f, a1 = 0.f;

  if (deg <= DEG_CAP) {
    // pass 1: compute logits (vectorized), stash in LDS, track max only
    float m0 = -1e30f, m1 = -1e30f, m2 = -1e30f, m3 = -1e30f;
    for (int e = lo + lane, j = lane; e < hi; e += 64, j += 64) {
      int src = esrc[e];
      int id = eeid[e];
      float4 lsv = *(const float4*)(ls + (size_t)src * 4);
      float4 lev = *(const float4*)(le + (size_t)id * 4);
      float g0 = lsv.x + ldn.x + lev.x; g0 = g0 > 0.f ? g0 : 0.2f * g0;
      float g1 = lsv.y + ldn.y + lev.y; g1 = g1 > 0.f ? g1 : 0.2f * g1;
      float g2 = lsv.z + ldn.z + lev.z; g2 = g2 > 0.f ? g2 : 0.2f * g2;
      float g3 = lsv.w + ldn.w + lev.w; g3 = g3 > 0.f ? g3 : 0.2f * g3;
      ((float4*)gl)[j] = make_float4(g0, g1, g2, g3);
      m0 = fmaxf(m0, g0); m1 = fmaxf(m1, g1); m2 = fmaxf(m2, g2); m3 = fmaxf(m3, g3);
    }
#pragma unroll
    for (int off = 1; off < 64; off <<= 1) {
      m0 = fmaxf(m0, __shfl_xor(m0, off));
      m1 = fmaxf(m1, __shfl_xor(m1, off));
      m2 = fmaxf(m2, __shfl_xor(m2, off));
      m3 = fmaxf(m3, __shfl_xor(m3, off));
    }
    if (m0 < -1e29f) m0 = 0.f;
    if (m1 < -1e29f) m1 = 0.f;
    if (m2 < -1e29f) m2 = 0.f;
    if (m3 < -1e29f) m3 = 0.f;
    float mh = h == 0 ? m0 : (h == 1 ? m1 : (h == 2 ? m2 : m3));

    // phase A: alpha = exp(g - m) once per (edge, head); partial sums per lane
    float sacc = 0.f;
    int je = lane & 15;
    for (int j0 = 0; j0 < deg; j0 += 16) {
      int j = j0 + je;
      if (j < deg) {
        float g = gl[j * 4 + h];
        float a = __expf(g - mh);
        gl[j * 4 + h] = a;
        sacc += a;
      }
    }
#pragma unroll
    for (int off = 1; off < 16; off <<= 1) sacc += __shfl_xor(sacc, off);
    float rdh = 1.0f / (sacc + 1e-16f);

    // phase B: gather hp rows, weight by LDS alpha (normalize at the end)
    for (int e = lo, j = 0; e < hi; ++e, ++j) {
      int src = esrc[e];
      float alpha = gl[j * 4 + h];
      float2 v = *(const float2*)(hp + (size_t)src * 128 + col);
      a0 += alpha * v.x;
      a1 += alpha * v.y;
    }
    a0 *= rdh;
    a1 *= rdh;
  } else {
    // slow path (deg > DEG_CAP): online softmax + recompute gather
    float m0 = -1e30f, m1 = -1e30f, m2 = -1e30f, m3 = -1e30f;
    float s0 = 0.f, s1 = 0.f, s2 = 0.f, s3 = 0.f;
    for (int e = lo + lane; e < hi; e += 64) {
      int src = esrc[e];
      int id = eeid[e];
      float4 lsv = *(const float4*)(ls + (size_t)src * 4);
      float4 lev = *(const float4*)(le + (size_t)id * 4);
      float g0 = lsv.x + ldn.x + lev.x; g0 = g0 > 0.f ? g0 : 0.2f * g0;
      float g1 = lsv.y + ldn.y + lev.y; g1 = g1 > 0.f ? g1 : 0.2f * g1;
      float g2 = lsv.z + ldn.z + lev.z; g2 = g2 > 0.f ? g2 : 0.2f * g2;
      float g3 = lsv.w + ldn.w + lev.w; g3 = g3 > 0.f ? g3 : 0.2f * g3;
      float nm;
      nm = fmaxf(m0, g0); s0 = s0 * __expf(m0 - nm) + __expf(g0 - nm); m0 = nm;
      nm = fmaxf(m1, g1); s1 = s1 * __expf(m1 - nm) + __expf(g1 - nm); m1 = nm;
      nm = fmaxf(m2, g2); s2 = s2 * __expf(m2 - nm) + __expf(g2 - nm); m2 = nm;
      nm = fmaxf(m3, g3); s3 = s3 * __expf(m3 - nm) + __expf(g3 - nm); m3 = nm;
    }
#pragma unroll
    for (int off = 1; off < 64; off <<= 1) {
      float om, os, nm;
      om = __shfl_xor(m0, off); os = __shfl_xor(s0, off);
      nm = fmaxf(m0, om); s0 = s0 * __expf(m0 - nm) + os * __expf(om - nm); m0 = nm;
      om = __shfl_xor(m1, off); os = __shfl_xor(s1, off);
      nm = fmaxf(m1, om); s1 = s1 * __expf(m1 - nm) + os * __expf(om - nm); m1 = nm;
      om = __shfl_xor(m2, off); os = __shfl_xor(s2, off);
      nm = fmaxf(m2, om); s2 = s2 * __expf(m2 - nm) + os * __expf(om - nm); m2 = nm;
      om = __shfl_xor(m3, off); os = __shfl_xor(s3, off);
      nm = fmaxf(m3, om); s3 = s3 * __expf(m3 - nm) + os * __expf(om - nm); m3 = nm;
    }
    if (m0 < -1e29f) m0 = 0.f;
    if (m1 < -1e29f) m1 = 0.f;
    if (m2 < -1e29f) m2 = 0.f;
    if (m3 < -1e29f) m3 = 0.f;
    s0 += 1e-16f; s1 += 1e-16f; s2 += 1e-16f; s3 += 1e-16f;
    float mh = h == 0 ? m0 : (h == 1 ? m1 : (h == 2 ? m2 : m3));
    float rdh = 1.0f / (h == 0 ? s0 : (h == 1 ? s1 : (h == 2 ? s2 : s3)));
    for (int e = lo; e < hi; ++e) {
      int src = esrc[e];
      int id = eeid[e];
      float g = ls[(size_t)src * 4 + h] + ldh + le[(size_t)id * 4 + h];
      g = g > 0.f ? g : 0.2f * g;
      float alpha = __expf(g - mh) * rdh;
      float2 v = *(const float2*)(hp + (size_t)src * 128 + col);
      a0 += alpha * v.x;
      a1 += alpha * v.y;
    }
  }

  float o0 = a0 + bias[col];
  float o1 = a1 + bias[col + 1];
  if (do_elu) {
    o0 = o0 > 0.f ? o0 : expm1f(o0);
    o1 = o1 > 0.f ? o1 : expm1f(o1);
  }
  *(float2*)(out + (size_t)wid * 128 + col) = make_float2(o0, o1);
}

// ---------- loc head: relu(h@Wl1+bl1)@Wl2+bl2, wave per node ----------
__global__ __launch_bounds__(256) void loc_kernel(
    const float* __restrict__ h, const float* __restrict__ Wl1,
    const float* __restrict__ bl1, const float* __restrict__ Wl2,
    const float* __restrict__ bl2, float* __restrict__ out, int n) {
  int wid = (blockIdx.x * blockDim.x + threadIdx.x) >> 6;
  int lane = threadIdx.x & 63;
  if (wid >= n) return;
  const float* hr = h + (size_t)wid * 128;
  float ac0 = 0.f, ac1 = 0.f, ac2 = 0.f, ac3 = 0.f;  // 4 accs: break dep chain
  for (int k = 0; k < 128; k += 4) {
    float4 hv = *(const float4*)(hr + k);
    ac0 += hv.x * Wl1[(k + 0) * 64 + lane];
    ac1 += hv.y * Wl1[(k + 1) * 64 + lane];
    ac2 += hv.z * Wl1[(k + 2) * 64 + lane];
    ac3 += hv.w * Wl1[(k + 3) * 64 + lane];
  }
  float acc = bl1[lane] + ((ac0 + ac1) + (ac2 + ac3));
  acc = fmaxf(acc, 0.f) * Wl2[lane];
#pragma unroll
  for (int off = 1; off < 64; off <<= 1) acc += __shfl_xor(acc, off);
  if (lane == 0) out[wid] = acc + bl2[0];
}

// ---------- class head: zero -> parallel segment-sum pool -> tiny MLP ----------
__global__ void zero_gemb_kernel(float* gemb) {
  int i = blockIdx.x * blockDim.x + threadIdx.x;
  if (i < 64 * 128) gemb[i] = 0.f;
}

// 128 threads (one per column); each block accumulates a 128-node slab of the
// sorted-batch node list in registers and flushes per group boundary.
__global__ __launch_bounds__(128) void pool_kernel(
    const float* __restrict__ h, const int* __restrict__ batch,
    float* __restrict__ gemb, int n) {
  int t = threadIdx.x;
  int base = blockIdx.x * 128;
  int end = base + 128 < n ? base + 128 : n;
  float acc = 0.f;
  int cur = -1;
  for (int node = base; node < end; ++node) {
    int g = batch[node];
    if (g != cur) {
      if (cur >= 0) atomicAdd(&gemb[cur * 128 + t], acc);
      acc = 0.f;
      cur = g;
    }
    acc += h[(size_t)node * 128 + t];
  }
  if (cur >= 0) atomicAdd(&gemb[cur * 128 + t], acc);
}

__global__ __launch_bounds__(128) void class_mlp_kernel(
    const float* __restrict__ gsum, const int* __restrict__ batch,
    const float* __restrict__ Wc1, const float* __restrict__ bc1,
    const float* __restrict__ Wc2, const float* __restrict__ bc2,
    float* __restrict__ out, int n) {
  int g = blockIdx.x;
  int t = threadIdx.x;
  // count nodes in group g via binary search (batch sorted)
  int lo = 0, hi = n;
  while (lo < hi) { int mid = (lo + hi) >> 1; if (batch[mid] < g) lo = mid + 1; else hi = mid; }
  int a = lo, b2 = n;
  while (a < b2) { int mid = (a + b2) >> 1; if (batch[mid] < g + 1) a = mid + 1; else b2 = mid; }
  int cnt = a - lo;
  float denom = cnt > 0 ? (float)cnt : 1.f;
  __shared__ float gemb[128];
  __shared__ float hidl[128];
  gemb[t] = gsum[g * 128 + t] / denom;
  __syncthreads();
  float hid = bc1[t];
  for (int k = 0; k < 128; ++k) hid += gemb[k] * Wc1[k * 128 + t];
  hidl[t] = fmaxf(hid, 0.f);
  __syncthreads();
  if (t < 10) {
    float o = bc2[t];
    for (int k = 0; k < 128; ++k) o += hidl[k] * Wc2[k * 10 + t];
    out[g * 10 + t] = o;
  }
}

extern "C" void kernel_launch(void* const* d_in, const int* in_sizes, int n_in,
                              void* d_out, int out_size, void* d_ws, size_t ws_size,
                              hipStream_t stream) {
  const float* x = (const float*)d_in[0];
  const int* ei = (const int*)d_in[1];
  const float* ea = (const float*)d_in[2];
  const int* batch = (const int*)d_in[3];
  const float* W[3]  = {(const float*)d_in[4],  (const float*)d_in[10], (const float*)d_in[16]};
  const float* aS[3] = {(const float*)d_in[5],  (const float*)d_in[11], (const float*)d_in[17]};
  const float* aD[3] = {(const float*)d_in[6],  (const float*)d_in[12], (const float*)d_in[18]};
  const float* We[3] = {(const float*)d_in[7],  (const float*)d_in[13], (const float*)d_in[19]};
  const float* aE[3] = {(const float*)d_in[8],  (const float*)d_in[14], (const float*)d_in[20]};
  const float* bb[3] = {(const float*)d_in[9],  (const float*)d_in[15], (const float*)d_in[21]};
  const float* Wc1 = (const float*)d_in[22];
  const float* bc1 = (const float*)d_in[23];
  const float* Wc2 = (const float*)d_in[24];
  const float* bc2 = (const float*)d_in[25];
  const float* Wl1 = (const float*)d_in[26];
  const float* bl1 = (const float*)d_in[27];
  const float* Wl2 = (const float*)d_in[28];
  const float* bl2 = (const float*)d_in[29];

  const int N = in_sizes[0] / 64;
  const int E = in_sizes[1] / 2;
  const int EP = E + N;

  char* p = (char*)d_ws;
  auto alloc = [&](size_t bytes) {
    char* r = p;
    p += (bytes + 255) & ~(size_t)255;
    return r;
  };
  float* A      = (float*)alloc((size_t)N * 128 * 4);  // layer io
  float* hp     = (float*)alloc((size_t)N * 128 * 4);  // projected features
  float* ls     = (float*)alloc((size_t)N * 4 * 4);
  float* ldv    = (float*)alloc((size_t)N * 4 * 4);
  float* le     = (float*)alloc((size_t)(E + 1) * 4 * 4);  // row E = self-loop le
  int* rowptr   = (int*)alloc((size_t)(N + 1) * 4);
  int* cursor   = (int*)alloc((size_t)N * 4);  // doubles as degree count
  int* bsum     = (int*)alloc(256 * 4);
  int* esrc     = (int*)alloc((size_t)EP * 4);
  int* eeid     = (int*)alloc((size_t)EP * 4);
  float* m_acc  = (float*)alloc(16 * 4);
  float* gemb   = (float*)alloc(64 * 128 * 4);

  float* out_cls = (float*)d_out;
  float* out_loc = (float*)d_out + 640;

  int nb = (N + SCAN_TILE - 1) / SCAN_TILE;

  init_cnt_kernel<<<(N + 255) / 256, 256, 0, stream>>>(cursor, m_acc, N);
  count_kernel<<<1024, 256, 0, stream>>>(ei + E, cursor, E);
  scan1_kernel<<<nb, 256, 0, stream>>>(cursor, rowptr, bsum, N);
  scan2_kernel<<<1, 64, 0, stream>>>(bsum, nb, rowptr);
  scan3_kernel<<<nb, 256, 0, stream>>>(bsum, rowptr, cursor, N);
  scatter_kernel<<<2048, 256, 0, stream>>>(ei, cursor, esrc, eeid, E, N);

  for (int l = 0; l < 3; ++l) {
    if (l == 0)
      le_kernel<true><<<2048, 256, 0, stream>>>(ea, We[0], aE[0], le, m_acc, E);
    else
      le_kernel<false><<<2048, 256, 0, stream>>>(ea, We[l], aE[l], le, nullptr, E);
    le_self_kernel<<<1, 64, 0, stream>>>(m_acc, 1.0f / (float)E, We[l], aE[l], le, E);
    if (l == 0)
      proj_kernel<64><<<(N + 7) / 8, 128, 0, stream>>>(x, W[0], aS[0], aD[0], hp, ls, ldv, N);
    else
      proj_kernel<128><<<(N + 7) / 8, 128, 0, stream>>>(A, W[l], aS[l], aD[l], hp, ls, ldv, N);
    agg_kernel<<<(N * 64 + 255) / 256, 256, 0, stream>>>(
        hp, ls, ldv, le, rowptr, esrc, eeid, bb[l], A, N, l < 2 ? 1 : 0);
  }

  loc_kernel<<<(N * 64 + 255) / 256, 256, 0, stream>>>(A, Wl1, bl1, Wl2, bl2, out_loc, N);
  zero_gemb_kernel<<<32, 256, 0, stream>>>(gemb);
  pool_kernel<<<(N + 127) / 128, 128, 0, stream>>>(A, batch, gemb, N);
  class_mlp_kernel<<<64, 128, 0, stream>>>(gemb, batch, Wc1, bc1, Wc2, bc2, out_cls, N);
}

// Round 5
// 1456.414 us; speedup vs baseline: 1.4040x; 1.0184x over previous
//
#include <hip/hip_runtime.h>
#include <math.h>

// GridGNN: 3x GATConv(H=4,C=32,concat) + ELU between, then node-level MLP head
// (loc_logits) and graph-pool MLP head (class_logits).
// Strategy: build CSR by dst once (counting sort); wave-per-node aggregation
// with LDS-cached logits; le for all 3 layers computed in ONE edge_attr pass;
// loc head as register-tiled GEMM; class head: parallel pool + tiny MLP.

constexpr int SCAN_TILE = 2048;  // 256 threads * 8 elements
constexpr int DEG_CAP = 128;     // LDS logit slab per wave; deg>CAP -> slow path

// ---------- CSR build ----------
__global__ void init_cnt_kernel(int* cnt, float* mean_acc, int n) {
  int i = blockIdx.x * blockDim.x + threadIdx.x;
  if (i < n) cnt[i] = 1;  // every node gets one self-loop
  if (blockIdx.x == 0 && threadIdx.x < 16) mean_acc[threadIdx.x] = 0.f;
}

__global__ void count_kernel(const int* __restrict__ dst, int* cnt, int E) {
  int stride = gridDim.x * blockDim.x;
  for (int e = blockIdx.x * blockDim.x + threadIdx.x; e < E; e += stride)
    atomicAdd(&cnt[dst[e]], 1);
}

__global__ void scan1_kernel(const int* __restrict__ cnt, int* rowptr, int* bsum, int n) {
  __shared__ int part[256];
  int t = threadIdx.x, b = blockIdx.x;
  int base = b * SCAN_TILE + t * 8;
  int v[8];
  int s = 0;
#pragma unroll
  for (int i = 0; i < 8; ++i) {
    int idx = base + i;
    v[i] = (idx < n) ? cnt[idx] : 0;
    s += v[i];
  }
  part[t] = s;
  __syncthreads();
  if (t == 0) {
    int run = 0;
    for (int i = 0; i < 256; ++i) { int x = part[i]; part[i] = run; run += x; }
    bsum[b] = run;
  }
  __syncthreads();
  int run = part[t];
#pragma unroll
  for (int i = 0; i < 8; ++i) {
    int idx = base + i;
    run += v[i];
    if (idx < n) rowptr[idx + 1] = run;
  }
}

__global__ void scan2_kernel(int* bsum, int nb, int* rowptr) {
  if (threadIdx.x == 0 && blockIdx.x == 0) {
    rowptr[0] = 0;
    int run = 0;
    for (int b = 0; b < nb; ++b) { int x = bsum[b]; bsum[b] = run; run += x; }
  }
}

// adds block offsets AND initializes the scatter cursor (fold of copy_cursor)
__global__ void scan3_kernel(const int* __restrict__ bsum, int* rowptr, int* cursor, int n) {
  int off = bsum[blockIdx.x];
  int base = blockIdx.x * SCAN_TILE + threadIdx.x * 8;
#pragma unroll
  for (int i = 0; i < 8; ++i) {
    int idx = base + i;
    if (idx < n) {
      int v = rowptr[idx + 1] + off;
      rowptr[idx + 1] = v;
      if (idx + 1 < n) cursor[idx + 1] = v;
    }
  }
  if (blockIdx.x == 0 && threadIdx.x == 0) cursor[0] = 0;
}

__global__ void scatter_kernel(const int* __restrict__ ei, int* cursor,
                               int* esrc, int* eeid, int E, int n) {
  int stride = gridDim.x * blockDim.x;
  int total = E + n;
  for (int i = blockIdx.x * blockDim.x + threadIdx.x; i < total; i += stride) {
    int s, d, id;
    if (i < E) { s = ei[i]; d = ei[E + i]; id = i; }
    else       { s = i - E; d = s; id = E; }  // self loop; le row E = self le
    int pos = atomicAdd(&cursor[d], 1);
    esrc[pos] = s;
    eeid[pos] = id;
  }
}

// ---------- le for ALL 3 layers in one edge_attr pass ----------
// le_l[e,h] = (ea @ We_l) . aE_l == ea @ wered_l[16,4]; also accumulates
// column sums of ea into m_acc (self-loop fill value).
__global__ void le_all_kernel(
    const float* __restrict__ ea,
    const float* __restrict__ We0, const float* __restrict__ aE0,
    const float* __restrict__ We1, const float* __restrict__ aE1,
    const float* __restrict__ We2, const float* __restrict__ aE2,
    float* __restrict__ le0, float* __restrict__ le1, float* __restrict__ le2,
    float* __restrict__ m_acc, int E) {
  __shared__ float wr[3][16][4];
  int t = threadIdx.x;
  if (t < 192) {
    int l = t >> 6, r = t & 63, f = r >> 2, hh = r & 3;
    const float* We = l == 0 ? We0 : (l == 1 ? We1 : We2);
    const float* aE = l == 0 ? aE0 : (l == 1 ? aE1 : aE2);
    float s = 0.f;
    for (int c = 0; c < 32; ++c) s += We[f * 128 + hh * 32 + c] * aE[hh * 32 + c];
    wr[l][f][hh] = s;
  }
  __syncthreads();
  float a[16];
#pragma unroll
  for (int i = 0; i < 16; ++i) a[i] = 0.f;
  int stride = gridDim.x * blockDim.x;
  for (int e = blockIdx.x * blockDim.x + t; e < E; e += stride) {
    const float4* p = (const float4*)(ea + (size_t)e * 16);
    float4 x0 = p[0], x1 = p[1], x2 = p[2], x3 = p[3];
    float xf[16] = {x0.x, x0.y, x0.z, x0.w, x1.x, x1.y, x1.z, x1.w,
                    x2.x, x2.y, x2.z, x2.w, x3.x, x3.y, x3.z, x3.w};
#pragma unroll
    for (int i = 0; i < 16; ++i) a[i] += xf[i];
#pragma unroll
    for (int l = 0; l < 3; ++l) {
      float oo[4];
#pragma unroll
      for (int hh = 0; hh < 4; ++hh) {
        float s = 0.f;
#pragma unroll
        for (int f = 0; f < 16; ++f) s += xf[f] * wr[l][f][hh];
        oo[hh] = s;
      }
      float* le = l == 0 ? le0 : (l == 1 ? le1 : le2);
      *(float4*)(le + (size_t)e * 4) = make_float4(oo[0], oo[1], oo[2], oo[3]);
    }
  }
  __shared__ float sm[16];
  if (t < 16) sm[t] = 0.f;
  __syncthreads();
#pragma unroll
  for (int i = 0; i < 16; ++i) atomicAdd(&sm[i], a[i]);
  __syncthreads();
  if (t < 16) atomicAdd(&m_acc[t], sm[t]);
}

// self-loop le rows for all 3 layers (row E of each slab)
__global__ void le_self_all_kernel(
    const float* __restrict__ mean_acc, float scale,
    const float* __restrict__ We0, const float* __restrict__ aE0,
    const float* __restrict__ We1, const float* __restrict__ aE1,
    const float* __restrict__ We2, const float* __restrict__ aE2,
    float* __restrict__ le0, float* __restrict__ le1, float* __restrict__ le2,
    int E) {
  int t = threadIdx.x;
  if (t < 12) {
    int l = t >> 2, hh = t & 3;
    const float* We = l == 0 ? We0 : (l == 1 ? We1 : We2);
    const float* aE = l == 0 ? aE0 : (l == 1 ? aE1 : aE2);
    float* le = l == 0 ? le0 : (l == 1 ? le1 : le2);
    float s = 0.f;
    for (int f = 0; f < 16; ++f) {
      float w = 0.f;
      for (int c = 0; c < 32; ++c) w += We[f * 128 + hh * 32 + c] * aE[hh * 32 + c];
      s += mean_acc[f] * scale * w;
    }
    le[(size_t)E * 4 + hh] = s;
  }
}

// ---------- fallback per-layer le (used only if ws too small for 3 slabs) ----
template <bool MEAN>
__global__ void le_kernel(const float* __restrict__ ea, const float* __restrict__ We,
                          const float* __restrict__ aE, float* __restrict__ le,
                          float* __restrict__ m_acc, int E) {
  __shared__ float wr[16][4];
  int t = threadIdx.x;
  if (t < 64) {
    int f = t >> 2, h = t & 3;
    float s = 0.f;
    for (int c = 0; c < 32; ++c) s += We[f * 128 + h * 32 + c] * aE[h * 32 + c];
    wr[f][h] = s;
  }
  __syncthreads();
  float a[16];
  if (MEAN) {
#pragma unroll
    for (int i = 0; i < 16; ++i) a[i] = 0.f;
  }
  int stride = gridDim.x * blockDim.x;
  for (int e = blockIdx.x * blockDim.x + t; e < E; e += stride) {
    const float4* p = (const float4*)(ea + (size_t)e * 16);
    float4 x0 = p[0], x1 = p[1], x2 = p[2], x3 = p[3];
    float xf[16] = {x0.x, x0.y, x0.z, x0.w, x1.x, x1.y, x1.z, x1.w,
                    x2.x, x2.y, x2.z, x2.w, x3.x, x3.y, x3.z, x3.w};
    if (MEAN) {
#pragma unroll
      for (int i = 0; i < 16; ++i) a[i] += xf[i];
    }
    float oo[4];
#pragma unroll
    for (int h = 0; h < 4; ++h) {
      float s = 0.f;
#pragma unroll
      for (int f = 0; f < 16; ++f) s += xf[f] * wr[f][h];
      oo[h] = s;
    }
    *(float4*)(le + (size_t)e * 4) = make_float4(oo[0], oo[1], oo[2], oo[3]);
  }
  if (MEAN) {
    __shared__ float sm[16];
    if (t < 16) sm[t] = 0.f;
    __syncthreads();
#pragma unroll
    for (int i = 0; i < 16; ++i) atomicAdd(&sm[i], a[i]);
    __syncthreads();
    if (t < 16) atomicAdd(&m_acc[t], sm[t]);
  }
}

__global__ void le_self_kernel(const float* __restrict__ mean_acc, float scale,
                               const float* __restrict__ We, const float* __restrict__ aE,
                               float* __restrict__ le, int E) {
  int t = threadIdx.x;
  if (t < 4) {
    float s = 0.f;
    for (int f = 0; f < 16; ++f) {
      float w = 0.f;
      for (int c = 0; c < 32; ++c) w += We[f * 128 + t * 32 + c] * aE[t * 32 + c];
      s += mean_acc[f] * scale * w;
    }
    le[(size_t)E * 4 + t] = s;
  }
}

// ---------- node projection GEMM + fused alpha_src/alpha_dst ----------
template <int K>
__global__ __launch_bounds__(128) void proj_kernel(
    const float* __restrict__ in, const float* __restrict__ W,
    const float* __restrict__ aS, const float* __restrict__ aD,
    float* __restrict__ hp, float* __restrict__ ls, float* __restrict__ ldv, int n) {
  __shared__ float xs[8][K];
  int t = threadIdx.x;
  int base = blockIdx.x * 8;
  for (int idx = t; idx < 8 * K; idx += 128) {
    int r = idx / K, k = idx - r * K;
    int row = base + r;
    xs[r][k] = (row < n) ? in[(size_t)row * K + k] : 0.f;
  }
  __syncthreads();
  float acc[8];
#pragma unroll
  for (int r = 0; r < 8; ++r) acc[r] = 0.f;
  for (int k = 0; k < K; ++k) {
    float w = W[k * 128 + t];
#pragma unroll
    for (int r = 0; r < 8; ++r) acc[r] += xs[r][k] * w;
  }
  float sA = aS[t], sD = aD[t];
  int h = t >> 5;
#pragma unroll
  for (int r = 0; r < 8; ++r) {
    int row = base + r;
    if (row < n) hp[(size_t)row * 128 + t] = acc[r];
    float vS = acc[r] * sA;
    float vD = acc[r] * sD;
#pragma unroll
    for (int off = 1; off < 32; off <<= 1) {
      vS += __shfl_xor(vS, off);
      vD += __shfl_xor(vD, off);
    }
    if ((t & 31) == 0 && row < n) {
      ls[(size_t)row * 4 + h] = vS;
      ldv[(size_t)row * 4 + h] = vD;
    }
  }
}

// ---------- wave-per-node aggregation with LDS-cached logits ----------
__global__ __launch_bounds__(256) void agg_kernel(
    const float* __restrict__ hp, const float* __restrict__ ls,
    const float* __restrict__ ldv, const float* __restrict__ le,
    const int* __restrict__ rowptr, const int* __restrict__ esrc,
    const int* __restrict__ eeid, const float* __restrict__ bias,
    float* __restrict__ out, int n, int do_elu) {
  __shared__ float gall[4][DEG_CAP * 4];  // per-wave logit/alpha slab (8 KB)
  float* gl = gall[threadIdx.x >> 6];
  int wid = (blockIdx.x * blockDim.x + threadIdx.x) >> 6;
  int lane = threadIdx.x & 63;
  if (wid >= n) return;
  int lo = rowptr[wid], hi = rowptr[wid + 1];
  int deg = hi - lo;
  float4 ldn = *(const float4*)(ldv + (size_t)wid * 4);
  int h = lane >> 4;  // head for gather phase: lane covers cols [2*lane,2*lane+1]
  int col = lane * 2;
  float ldh = h == 0 ? ldn.x : (h == 1 ? ldn.y : (h == 2 ? ldn.z : ldn.w));
  float a0 = 0.f, a1 = 0.f;

  if (deg <= DEG_CAP) {
    // pass 1: compute logits (vectorized), stash in LDS, track max only
    float m0 = -1e30f, m1 = -1e30f, m2 = -1e30f, m3 = -1e30f;
    for (int e = lo + lane, j = lane; e < hi; e += 64, j += 64) {
      int src = esrc[e];
      int id = eeid[e];
      float4 lsv = *(const float4*)(ls + (size_t)src * 4);
      float4 lev = *(const float4*)(le + (size_t)id * 4);
      float g0 = lsv.x + ldn.x + lev.x; g0 = g0 > 0.f ? g0 : 0.2f * g0;
      float g1 = lsv.y + ldn.y + lev.y; g1 = g1 > 0.f ? g1 : 0.2f * g1;
      float g2 = lsv.z + ldn.z + lev.z; g2 = g2 > 0.f ? g2 : 0.2f * g2;
      float g3 = lsv.w + ldn.w + lev.w; g3 = g3 > 0.f ? g3 : 0.2f * g3;
      ((float4*)gl)[j] = make_float4(g0, g1, g2, g3);
      m0 = fmaxf(m0, g0); m1 = fmaxf(m1, g1); m2 = fmaxf(m2, g2); m3 = fmaxf(m3, g3);
    }
#pragma unroll
    for (int off = 1; off < 64; off <<= 1) {
      m0 = fmaxf(m0, __shfl_xor(m0, off));
      m1 = fmaxf(m1, __shfl_xor(m1, off));
      m2 = fmaxf(m2, __shfl_xor(m2, off));
      m3 = fmaxf(m3, __shfl_xor(m3, off));
    }
    if (m0 < -1e29f) m0 = 0.f;
    if (m1 < -1e29f) m1 = 0.f;
    if (m2 < -1e29f) m2 = 0.f;
    if (m3 < -1e29f) m3 = 0.f;
    float mh = h == 0 ? m0 : (h == 1 ? m1 : (h == 2 ? m2 : m3));

    // phase A: alpha = exp(g - m) once per (edge, head); partial sums per lane
    float sacc = 0.f;
    int je = lane & 15;
    for (int j0 = 0; j0 < deg; j0 += 16) {
      int j = j0 + je;
      if (j < deg) {
        float g = gl[j * 4 + h];
        float a = __expf(g - mh);
        gl[j * 4 + h] = a;
        sacc += a;
      }
    }
#pragma unroll
    for (int off = 1; off < 16; off <<= 1) sacc += __shfl_xor(sacc, off);
    float rdh = 1.0f / (sacc + 1e-16f);

    // phase B: gather hp rows, weight by LDS alpha (normalize at the end)
    for (int e = lo, j = 0; e < hi; ++e, ++j) {
      int src = esrc[e];
      float alpha = gl[j * 4 + h];
      float2 v = *(const float2*)(hp + (size_t)src * 128 + col);
      a0 += alpha * v.x;
      a1 += alpha * v.y;
    }
    a0 *= rdh;
    a1 *= rdh;
  } else {
    // slow path (deg > DEG_CAP): online softmax + recompute gather
    float m0 = -1e30f, m1 = -1e30f, m2 = -1e30f, m3 = -1e30f;
    float s0 = 0.f, s1 = 0.f, s2 = 0.f, s3 = 0.f;
    for (int e = lo + lane; e < hi; e += 64) {
      int src = esrc[e];
      int id = eeid[e];
      float4 lsv = *(const float4*)(ls + (size_t)src * 4);
      float4 lev = *(const float4*)(le + (size_t)id * 4);
      float g0 = lsv.x + ldn.x + lev.x; g0 = g0 > 0.f ? g0 : 0.2f * g0;
      float g1 = lsv.y + ldn.y + lev.y; g1 = g1 > 0.f ? g1 : 0.2f * g1;
      float g2 = lsv.z + ldn.z + lev.z; g2 = g2 > 0.f ? g2 : 0.2f * g2;
      float g3 = lsv.w + ldn.w + lev.w; g3 = g3 > 0.f ? g3 : 0.2f * g3;
      float nm;
      nm = fmaxf(m0, g0); s0 = s0 * __expf(m0 - nm) + __expf(g0 - nm); m0 = nm;
      nm = fmaxf(m1, g1); s1 = s1 * __expf(m1 - nm) + __expf(g1 - nm); m1 = nm;
      nm = fmaxf(m2, g2); s2 = s2 * __expf(m2 - nm) + __expf(g2 - nm); m2 = nm;
      nm = fmaxf(m3, g3); s3 = s3 * __expf(m3 - nm) + __expf(g3 - nm); m3 = nm;
    }
#pragma unroll
    for (int off = 1; off < 64; off <<= 1) {
      float om, os, nm;
      om = __shfl_xor(m0, off); os = __shfl_xor(s0, off);
      nm = fmaxf(m0, om); s0 = s0 * __expf(m0 - nm) + os * __expf(om - nm); m0 = nm;
      om = __shfl_xor(m1, off); os = __shfl_xor(s1, off);
      nm = fmaxf(m1, om); s1 = s1 * __expf(m1 - nm) + os * __expf(om - nm); m1 = nm;
      om = __shfl_xor(m2, off); os = __shfl_xor(s2, off);
      nm = fmaxf(m2, om); s2 = s2 * __expf(m2 - nm) + os * __expf(om - nm); m2 = nm;
      om = __shfl_xor(m3, off); os = __shfl_xor(s3, off);
      nm = fmaxf(m3, om); s3 = s3 * __expf(m3 - nm) + os * __expf(om - nm); m3 = nm;
    }
    if (m0 < -1e29f) m0 = 0.f;
    if (m1 < -1e29f) m1 = 0.f;
    if (m2 < -1e29f) m2 = 0.f;
    if (m3 < -1e29f) m3 = 0.f;
    s0 += 1e-16f; s1 += 1e-16f; s2 += 1e-16f; s3 += 1e-16f;
    float mh = h == 0 ? m0 : (h == 1 ? m1 : (h == 2 ? m2 : m3));
    float rdh = 1.0f / (h == 0 ? s0 : (h == 1 ? s1 : (h == 2 ? s2 : s3)));
    for (int e = lo; e < hi; ++e) {
      int src = esrc[e];
      int id = eeid[e];
      float g = ls[(size_t)src * 4 + h] + ldh + le[(size_t)id * 4 + h];
      g = g > 0.f ? g : 0.2f * g;
      float alpha = __expf(g - mh) * rdh;
      float2 v = *(const float2*)(hp + (size_t)src * 128 + col);
      a0 += alpha * v.x;
      a1 += alpha * v.y;
    }
  }

  float o0 = a0 + bias[col];
  float o1 = a1 + bias[col + 1];
  if (do_elu) {
    o0 = o0 > 0.f ? o0 : expm1f(o0);
    o1 = o1 > 0.f ? o1 : expm1f(o1);
  }
  *(float2*)(out + (size_t)wid * 128 + col) = make_float2(o0, o1);
}

// ---------- loc head: register-tiled GEMM  out[n] = relu(h@Wl1+bl1).Wl2+bl2 --
// block = 256 threads (16 hid-tiles x 16 node-tiles) -> 64 nodes x 64 hidden,
// K=128 in 4 chunks of 32 staged in LDS (h transposed [k][node], Wl1 [k][hid]).
__global__ __launch_bounds__(256) void loc_kernel(
    const float* __restrict__ h, const float* __restrict__ Wl1,
    const float* __restrict__ bl1, const float* __restrict__ Wl2,
    const float* __restrict__ bl2, float* __restrict__ out, int n) {
  __shared__ float hs[32][68];   // [k][node], pad 68 keeps b128 alignment
  __shared__ float ws[32][68];   // [k][hid]
  int t = threadIdx.x;
  int tx = t & 15;   // hid tile: hids tx*4..tx*4+3
  int ty = t >> 4;   // node tile: nodes ty*4..ty*4+3
  int nbase = blockIdx.x * 64;
  float acc[4][4];
#pragma unroll
  for (int i = 0; i < 4; ++i)
#pragma unroll
    for (int j = 0; j < 4; ++j) acc[i][j] = 0.f;

  for (int kc = 0; kc < 128; kc += 32) {
    __syncthreads();
    // stage h chunk transposed: 64 nodes x 32 k
    {
      int row = t >> 2;        // 0..63
      int q = t & 3;           // quads q and q+4 of this row's 8 quads
      int node = nbase + row;
      float4 v0 = make_float4(0.f, 0.f, 0.f, 0.f);
      float4 v1 = v0;
      if (node < n) {
        const float4* src = (const float4*)(h + (size_t)node * 128 + kc);
        v0 = src[q];
        v1 = src[q + 4];
      }
      int k0 = q * 4;
      hs[k0 + 0][row] = v0.x; hs[k0 + 1][row] = v0.y;
      hs[k0 + 2][row] = v0.z; hs[k0 + 3][row] = v0.w;
      hs[k0 + 16][row] = v1.x; hs[k0 + 17][row] = v1.y;
      hs[k0 + 18][row] = v1.z; hs[k0 + 19][row] = v1.w;
    }
    // stage Wl1 chunk: rows kc..kc+31 (32x64 floats, contiguous)
    {
      const float4* wsrc = (const float4*)(Wl1 + kc * 64);
#pragma unroll
      for (int q = 0; q < 2; ++q) {
        int idx = q * 256 + t;          // float4 index 0..511
        float4 v = wsrc[idx];
        int k = idx >> 4;               // 16 float4 per k-row
        int hid = (idx & 15) * 4;
        *(float4*)&ws[k][hid] = v;
      }
    }
    __syncthreads();
#pragma unroll
    for (int k = 0; k < 32; ++k) {
      float4 hv = *(const float4*)&hs[k][ty * 4];
      float4 wv = *(const float4*)&ws[k][tx * 4];
      acc[0][0] += hv.x * wv.x; acc[0][1] += hv.x * wv.y;
      acc[0][2] += hv.x * wv.z; acc[0][3] += hv.x * wv.w;
      acc[1][0] += hv.y * wv.x; acc[1][1] += hv.y * wv.y;
      acc[1][2] += hv.y * wv.z; acc[1][3] += hv.y * wv.w;
      acc[2][0] += hv.z * wv.x; acc[2][1] += hv.z * wv.y;
      acc[2][2] += hv.z * wv.z; acc[2][3] += hv.z * wv.w;
      acc[3][0] += hv.w * wv.x; acc[3][1] += hv.w * wv.y;
      acc[3][2] += hv.w * wv.z; acc[3][3] += hv.w * wv.w;
    }
  }
  // epilogue: relu(+bl1) . Wl2, reduce over the 16 hid-tiles (lanes tx)
  float4 b1 = *(const float4*)(bl1 + tx * 4);
  float4 w2 = *(const float4*)(Wl2 + tx * 4);
  float b2v = bl2[0];
#pragma unroll
  for (int i = 0; i < 4; ++i) {
    float s = fmaxf(acc[i][0] + b1.x, 0.f) * w2.x +
              fmaxf(acc[i][1] + b1.y, 0.f) * w2.y +
              fmaxf(acc[i][2] + b1.z, 0.f) * w2.z +
              fmaxf(acc[i][3] + b1.w, 0.f) * w2.w;
#pragma unroll
    for (int off = 1; off < 16; off <<= 1) s += __shfl_xor(s, off);
    int node = nbase + ty * 4 + i;
    if (tx == 0 && node < n) out[node] = s + b2v;
  }
}

// ---------- class head: zero -> parallel segment-sum pool -> tiny MLP ----------
__global__ void zero_gemb_kernel(float* gemb) {
  int i = blockIdx.x * blockDim.x + threadIdx.x;
  if (i < 64 * 128) gemb[i] = 0.f;
}

__global__ __launch_bounds__(128) void pool_kernel(
    const float* __restrict__ h, const int* __restrict__ batch,
    float* __restrict__ gemb, int n) {
  int t = threadIdx.x;
  int base = blockIdx.x * 128;
  int end = base + 128 < n ? base + 128 : n;
  float acc = 0.f;
  int cur = -1;
  for (int node = base; node < end; ++node) {
    int g = batch[node];
    if (g != cur) {
      if (cur >= 0) atomicAdd(&gemb[cur * 128 + t], acc);
      acc = 0.f;
      cur = g;
    }
    acc += h[(size_t)node * 128 + t];
  }
  if (cur >= 0) atomicAdd(&gemb[cur * 128 + t], acc);
}

__global__ __launch_bounds__(128) void class_mlp_kernel(
    const float* __restrict__ gsum, const int* __restrict__ batch,
    const float* __restrict__ Wc1, const float* __restrict__ bc1,
    const float* __restrict__ Wc2, const float* __restrict__ bc2,
    float* __restrict__ out, int n) {
  int g = blockIdx.x;
  int t = threadIdx.x;
  int lo = 0, hi = n;
  while (lo < hi) { int mid = (lo + hi) >> 1; if (batch[mid] < g) lo = mid + 1; else hi = mid; }
  int a = lo, b2 = n;
  while (a < b2) { int mid = (a + b2) >> 1; if (batch[mid] < g + 1) a = mid + 1; else b2 = mid; }
  int cnt = a - lo;
  float denom = cnt > 0 ? (float)cnt : 1.f;
  __shared__ float gemb[128];
  __shared__ float hidl[128];
  gemb[t] = gsum[g * 128 + t] / denom;
  __syncthreads();
  float hid = bc1[t];
  for (int k = 0; k < 128; ++k) hid += gemb[k] * Wc1[k * 128 + t];
  hidl[t] = fmaxf(hid, 0.f);
  __syncthreads();
  if (t < 10) {
    float o = bc2[t];
    for (int k = 0; k < 128; ++k) o += hidl[k] * Wc2[k * 10 + t];
    out[g * 10 + t] = o;
  }
}

extern "C" void kernel_launch(void* const* d_in, const int* in_sizes, int n_in,
                              void* d_out, int out_size, void* d_ws, size_t ws_size,
                              hipStream_t stream) {
  const float* x = (const float*)d_in[0];
  const int* ei = (const int*)d_in[1];
  const float* ea = (const float*)d_in[2];
  const int* batch = (const int*)d_in[3];
  const float* W[3]  = {(const float*)d_in[4],  (const float*)d_in[10], (const float*)d_in[16]};
  const float* aS[3] = {(const float*)d_in[5],  (const float*)d_in[11], (const float*)d_in[17]};
  const float* aD[3] = {(const float*)d_in[6],  (const float*)d_in[12], (const float*)d_in[18]};
  const float* We[3] = {(const float*)d_in[7],  (const float*)d_in[13], (const float*)d_in[19]};
  const float* aE[3] = {(const float*)d_in[8],  (const float*)d_in[14], (const float*)d_in[20]};
  const float* bb[3] = {(const float*)d_in[9],  (const float*)d_in[15], (const float*)d_in[21]};
  const float* Wc1 = (const float*)d_in[22];
  const float* bc1 = (const float*)d_in[23];
  const float* Wc2 = (const float*)d_in[24];
  const float* bc2 = (const float*)d_in[25];
  const float* Wl1 = (const float*)d_in[26];
  const float* bl1 = (const float*)d_in[27];
  const float* Wl2 = (const float*)d_in[28];
  const float* bl2 = (const float*)d_in[29];

  const int N = in_sizes[0] / 64;
  const int E = in_sizes[1] / 2;
  const int EP = E + N;

  char* p = (char*)d_ws;
  auto alloc = [&](size_t bytes) {
    char* r = p;
    p += (bytes + 255) & ~(size_t)255;
    return r;
  };
  float* A      = (float*)alloc((size_t)N * 128 * 4);  // layer io
  float* hp     = (float*)alloc((size_t)N * 128 * 4);  // projected features
  float* ls     = (float*)alloc((size_t)N * 4 * 4);
  float* ldv    = (float*)alloc((size_t)N * 4 * 4);
  float* le0    = (float*)alloc((size_t)(E + 1) * 4 * 4);  // row E = self-loop le
  int* rowptr   = (int*)alloc((size_t)(N + 1) * 4);
  int* cursor   = (int*)alloc((size_t)N * 4);
  int* bsum     = (int*)alloc(256 * 4);
  int* esrc     = (int*)alloc((size_t)EP * 4);
  int* eeid     = (int*)alloc((size_t)EP * 4);
  float* m_acc  = (float*)alloc(16 * 4);
  float* gemb   = (float*)alloc(64 * 128 * 4);
  // optional extra le slabs for the fused 3-layer edge pass
  size_t le_bytes = (((size_t)(E + 1) * 4 * 4) + 255) & ~(size_t)255;
  float* le1 = nullptr;
  float* le2 = nullptr;
  if ((size_t)(p - (char*)d_ws) + 2 * le_bytes <= ws_size) {
    le1 = (float*)alloc((size_t)(E + 1) * 4 * 4);
    le2 = (float*)alloc((size_t)(E + 1) * 4 * 4);
  }

  float* out_cls = (float*)d_out;
  float* out_loc = (float*)d_out + 640;

  int nb = (N + SCAN_TILE - 1) / SCAN_TILE;

  init_cnt_kernel<<<(N + 255) / 256, 256, 0, stream>>>(cursor, m_acc, N);
  count_kernel<<<1024, 256, 0, stream>>>(ei + E, cursor, E);
  scan1_kernel<<<nb, 256, 0, stream>>>(cursor, rowptr, bsum, N);
  scan2_kernel<<<1, 64, 0, stream>>>(bsum, nb, rowptr);
  scan3_kernel<<<nb, 256, 0, stream>>>(bsum, rowptr, cursor, N);
  scatter_kernel<<<2048, 256, 0, stream>>>(ei, cursor, esrc, eeid, E, N);

  if (le1) {
    le_all_kernel<<<2048, 256, 0, stream>>>(ea, We[0], aE[0], We[1], aE[1],
                                            We[2], aE[2], le0, le1, le2, m_acc, E);
    le_self_all_kernel<<<1, 64, 0, stream>>>(m_acc, 1.0f / (float)E,
                                             We[0], aE[0], We[1], aE[1],
                                             We[2], aE[2], le0, le1, le2, E);
  }

  for (int l = 0; l < 3; ++l) {
    float* leL = l == 0 ? le0 : (l == 1 ? (le1 ? le1 : le0) : (le2 ? le2 : le0));
    if (!le1) {  // fallback: per-layer le into le0
      if (l == 0)
        le_kernel<true><<<2048, 256, 0, stream>>>(ea, We[0], aE[0], le0, m_acc, E);
      else
        le_kernel<false><<<2048, 256, 0, stream>>>(ea, We[l], aE[l], le0, nullptr, E);
      le_self_kernel<<<1, 64, 0, stream>>>(m_acc, 1.0f / (float)E, We[l], aE[l], le0, E);
    }
    if (l == 0)
      proj_kernel<64><<<(N + 7) / 8, 128, 0, stream>>>(x, W[0], aS[0], aD[0], hp, ls, ldv, N);
    else
      proj_kernel<128><<<(N + 7) / 8, 128, 0, stream>>>(A, W[l], aS[l], aD[l], hp, ls, ldv, N);
    agg_kernel<<<(N * 64 + 255) / 256, 256, 0, stream>>>(
        hp, ls, ldv, leL, rowptr, esrc, eeid, bb[l], A, N, l < 2 ? 1 : 0);
  }

  loc_kernel<<<(N + 63) / 64, 256, 0, stream>>>(A, Wl1, bl1, Wl2, bl2, out_loc, N);
  zero_gemb_kernel<<<32, 256, 0, stream>>>(gemb);
  pool_kernel<<<(N + 127) / 128, 128, 0, stream>>>(A, batch, gemb, N);
  class_mlp_kernel<<<64, 128, 0, stream>>>(gemb, batch, Wc1, bc1, Wc2, bc2, out_cls, N);
}

// Round 6
// 1316.282 us; speedup vs baseline: 1.5534x; 1.1065x over previous
//
#include <hip/hip_runtime.h>
#include <math.h>

// GridGNN: 3x GATConv(H=4,C=32,concat) + ELU between, then node-level MLP head
// (loc_logits) and graph-pool MLP head (class_logits).
// Strategy: build CSR by dst once (counting sort); wave-per-node aggregation
// with LDS-cached logits; le for all 3 layers in ONE edge_attr pass with
// one-edge-per-thread (no spills); loc head as register-tiled GEMM; class
// head: parallel pool + tiny MLP.

constexpr int SCAN_TILE = 2048;  // 256 threads * 8 elements
constexpr int DEG_CAP = 128;     // LDS logit slab per wave; deg>CAP -> slow path

// ---------- CSR build ----------
__global__ void init_cnt_kernel(int* cnt, float* mean_acc, int n) {
  int i = blockIdx.x * blockDim.x + threadIdx.x;
  if (i < n) cnt[i] = 1;  // every node gets one self-loop
  if (blockIdx.x == 0 && threadIdx.x < 16) mean_acc[threadIdx.x] = 0.f;
}

__global__ void count_kernel(const int* __restrict__ dst, int* cnt, int E) {
  int stride = gridDim.x * blockDim.x;
  for (int e = blockIdx.x * blockDim.x + threadIdx.x; e < E; e += stride)
    atomicAdd(&cnt[dst[e]], 1);
}

__global__ void scan1_kernel(const int* __restrict__ cnt, int* rowptr, int* bsum, int n) {
  __shared__ int part[256];
  int t = threadIdx.x, b = blockIdx.x;
  int base = b * SCAN_TILE + t * 8;
  int v[8];
  int s = 0;
#pragma unroll
  for (int i = 0; i < 8; ++i) {
    int idx = base + i;
    v[i] = (idx < n) ? cnt[idx] : 0;
    s += v[i];
  }
  part[t] = s;
  __syncthreads();
  if (t == 0) {
    int run = 0;
    for (int i = 0; i < 256; ++i) { int x = part[i]; part[i] = run; run += x; }
    bsum[b] = run;
  }
  __syncthreads();
  int run = part[t];
#pragma unroll
  for (int i = 0; i < 8; ++i) {
    int idx = base + i;
    run += v[i];
    if (idx < n) rowptr[idx + 1] = run;
  }
}

__global__ void scan2_kernel(int* bsum, int nb, int* rowptr) {
  if (threadIdx.x == 0 && blockIdx.x == 0) {
    rowptr[0] = 0;
    int run = 0;
    for (int b = 0; b < nb; ++b) { int x = bsum[b]; bsum[b] = run; run += x; }
  }
}

// adds block offsets AND initializes the scatter cursor (fold of copy_cursor)
__global__ void scan3_kernel(const int* __restrict__ bsum, int* rowptr, int* cursor, int n) {
  int off = bsum[blockIdx.x];
  int base = blockIdx.x * SCAN_TILE + threadIdx.x * 8;
#pragma unroll
  for (int i = 0; i < 8; ++i) {
    int idx = base + i;
    if (idx < n) {
      int v = rowptr[idx + 1] + off;
      rowptr[idx + 1] = v;
      if (idx + 1 < n) cursor[idx + 1] = v;
    }
  }
  if (blockIdx.x == 0 && threadIdx.x == 0) cursor[0] = 0;
}

__global__ void scatter_kernel(const int* __restrict__ ei, int* cursor,
                               int* esrc, int* eeid, int E, int n) {
  int stride = gridDim.x * blockDim.x;
  int total = E + n;
  for (int i = blockIdx.x * blockDim.x + threadIdx.x; i < total; i += stride) {
    int s, d, id;
    if (i < E) { s = ei[i]; d = ei[E + i]; id = i; }
    else       { s = i - E; d = s; id = E; }  // self loop; le row E = self le
    int pos = atomicAdd(&cursor[d], 1);
    esrc[pos] = s;
    eeid[pos] = id;
  }
}

// ---------- le for ALL 3 layers, one edge per thread (no loop-carried regs) --
// le_l[e,h] = (ea @ We_l) . aE_l == ea @ wered_l[16,4]; per-block column sums
// of ea go to m_part[block][16] (contention-free), reduced by a tiny kernel.
__global__ __launch_bounds__(256) void le_all_kernel(
    const float* __restrict__ ea,
    const float* __restrict__ We0, const float* __restrict__ aE0,
    const float* __restrict__ We1, const float* __restrict__ aE1,
    const float* __restrict__ We2, const float* __restrict__ aE2,
    float* __restrict__ le0, float* __restrict__ le1, float* __restrict__ le2,
    float* __restrict__ m_part, int E) {
  __shared__ float wr[3][16][4];
  int t = threadIdx.x;
  if (t < 192) {
    int l = t >> 6, r = t & 63, f = r >> 2, hh = r & 3;
    const float* We = l == 0 ? We0 : (l == 1 ? We1 : We2);
    const float* aE = l == 0 ? aE0 : (l == 1 ? aE1 : aE2);
    float s = 0.f;
    for (int c = 0; c < 32; ++c) s += We[f * 128 + hh * 32 + c] * aE[hh * 32 + c];
    wr[l][f][hh] = s;
  }
  __syncthreads();

  int e = blockIdx.x * 256 + t;
  float xf[16];
  if (e < E) {
    const float4* p = (const float4*)(ea + (size_t)e * 16);
    float4 x0 = p[0], x1 = p[1], x2 = p[2], x3 = p[3];
    xf[0] = x0.x;  xf[1] = x0.y;  xf[2] = x0.z;  xf[3] = x0.w;
    xf[4] = x1.x;  xf[5] = x1.y;  xf[6] = x1.z;  xf[7] = x1.w;
    xf[8] = x2.x;  xf[9] = x2.y;  xf[10] = x2.z; xf[11] = x2.w;
    xf[12] = x3.x; xf[13] = x3.y; xf[14] = x3.z; xf[15] = x3.w;
#pragma unroll
    for (int l = 0; l < 3; ++l) {
      float oo[4];
#pragma unroll
      for (int hh = 0; hh < 4; ++hh) {
        float s = 0.f;
#pragma unroll
        for (int f = 0; f < 16; ++f) s += xf[f] * wr[l][f][hh];
        oo[hh] = s;
      }
      float* le = l == 0 ? le0 : (l == 1 ? le1 : le2);
      *(float4*)(le + (size_t)e * 4) = make_float4(oo[0], oo[1], oo[2], oo[3]);
    }
  } else {
#pragma unroll
    for (int i = 0; i < 16; ++i) xf[i] = 0.f;
  }

  // wave butterfly per column -> every lane holds the wave total of col i
#pragma unroll
  for (int i = 0; i < 16; ++i) {
#pragma unroll
    for (int off = 1; off < 64; off <<= 1) xf[i] += __shfl_xor(xf[i], off);
  }
  __shared__ float sm[16];
  if (t < 16) sm[t] = 0.f;
  __syncthreads();
  int lane = t & 63;
  if (lane < 16) atomicAdd(&sm[lane], xf[lane]);  // 4 waves x 16 LDS atomics
  __syncthreads();
  if (t < 16) m_part[(size_t)blockIdx.x * 16 + t] = sm[t];
}

// reduce m_part[nb][16] -> m_acc[16]
__global__ __launch_bounds__(256) void le_mean_reduce_kernel(
    const float* __restrict__ m_part, float* __restrict__ m_acc, int nb) {
  __shared__ float sm[16][17];
  int t = threadIdx.x;
  int col = t & 15, sl = t >> 4;
  float s = 0.f;
  for (int b = sl; b < nb; b += 16) s += m_part[(size_t)b * 16 + col];
  sm[sl][col] = s;
  __syncthreads();
  if (t < 16) {
    float tot = 0.f;
#pragma unroll
    for (int i = 0; i < 16; ++i) tot += sm[i][t];
    m_acc[t] = tot;
  }
}

// self-loop le rows for all 3 layers (row E of each slab)
__global__ void le_self_all_kernel(
    const float* __restrict__ mean_acc, float scale,
    const float* __restrict__ We0, const float* __restrict__ aE0,
    const float* __restrict__ We1, const float* __restrict__ aE1,
    const float* __restrict__ We2, const float* __restrict__ aE2,
    float* __restrict__ le0, float* __restrict__ le1, float* __restrict__ le2,
    int E) {
  int t = threadIdx.x;
  if (t < 12) {
    int l = t >> 2, hh = t & 3;
    const float* We = l == 0 ? We0 : (l == 1 ? We1 : We2);
    const float* aE = l == 0 ? aE0 : (l == 1 ? aE1 : aE2);
    float* le = l == 0 ? le0 : (l == 1 ? le1 : le2);
    float s = 0.f;
    for (int f = 0; f < 16; ++f) {
      float w = 0.f;
      for (int c = 0; c < 32; ++c) w += We[f * 128 + hh * 32 + c] * aE[hh * 32 + c];
      s += mean_acc[f] * scale * w;
    }
    le[(size_t)E * 4 + hh] = s;
  }
}

// ---------- fallback per-layer le (used only if ws too small for 3 slabs) ----
template <bool MEAN>
__global__ void le_kernel(const float* __restrict__ ea, const float* __restrict__ We,
                          const float* __restrict__ aE, float* __restrict__ le,
                          float* __restrict__ m_acc, int E) {
  __shared__ float wr[16][4];
  int t = threadIdx.x;
  if (t < 64) {
    int f = t >> 2, h = t & 3;
    float s = 0.f;
    for (int c = 0; c < 32; ++c) s += We[f * 128 + h * 32 + c] * aE[h * 32 + c];
    wr[f][h] = s;
  }
  __syncthreads();
  float a[16];
  if (MEAN) {
#pragma unroll
    for (int i = 0; i < 16; ++i) a[i] = 0.f;
  }
  int stride = gridDim.x * blockDim.x;
  for (int e = blockIdx.x * blockDim.x + t; e < E; e += stride) {
    const float4* p = (const float4*)(ea + (size_t)e * 16);
    float4 x0 = p[0], x1 = p[1], x2 = p[2], x3 = p[3];
    float xf[16] = {x0.x, x0.y, x0.z, x0.w, x1.x, x1.y, x1.z, x1.w,
                    x2.x, x2.y, x2.z, x2.w, x3.x, x3.y, x3.z, x3.w};
    if (MEAN) {
#pragma unroll
      for (int i = 0; i < 16; ++i) a[i] += xf[i];
    }
    float oo[4];
#pragma unroll
    for (int h = 0; h < 4; ++h) {
      float s = 0.f;
#pragma unroll
      for (int f = 0; f < 16; ++f) s += xf[f] * wr[f][h];
      oo[h] = s;
    }
    *(float4*)(le + (size_t)e * 4) = make_float4(oo[0], oo[1], oo[2], oo[3]);
  }
  if (MEAN) {
    __shared__ float sm[16];
    if (t < 16) sm[t] = 0.f;
    __syncthreads();
#pragma unroll
    for (int i = 0; i < 16; ++i) atomicAdd(&sm[i], a[i]);
    __syncthreads();
    if (t < 16) atomicAdd(&m_acc[t], sm[t]);
  }
}

__global__ void le_self_kernel(const float* __restrict__ mean_acc, float scale,
                               const float* __restrict__ We, const float* __restrict__ aE,
                               float* __restrict__ le, int E) {
  int t = threadIdx.x;
  if (t < 4) {
    float s = 0.f;
    for (int f = 0; f < 16; ++f) {
      float w = 0.f;
      for (int c = 0; c < 32; ++c) w += We[f * 128 + t * 32 + c] * aE[t * 32 + c];
      s += mean_acc[f] * scale * w;
    }
    le[(size_t)E * 4 + t] = s;
  }
}

// ---------- node projection GEMM + fused alpha_src/alpha_dst ----------
template <int K>
__global__ __launch_bounds__(128) void proj_kernel(
    const float* __restrict__ in, const float* __restrict__ W,
    const float* __restrict__ aS, const float* __restrict__ aD,
    float* __restrict__ hp, float* __restrict__ ls, float* __restrict__ ldv, int n) {
  __shared__ float xs[8][K];
  int t = threadIdx.x;
  int base = blockIdx.x * 8;
  for (int idx = t; idx < 8 * K; idx += 128) {
    int r = idx / K, k = idx - r * K;
    int row = base + r;
    xs[r][k] = (row < n) ? in[(size_t)row * K + k] : 0.f;
  }
  __syncthreads();
  float acc[8];
#pragma unroll
  for (int r = 0; r < 8; ++r) acc[r] = 0.f;
  for (int k = 0; k < K; ++k) {
    float w = W[k * 128 + t];
#pragma unroll
    for (int r = 0; r < 8; ++r) acc[r] += xs[r][k] * w;
  }
  float sA = aS[t], sD = aD[t];
  int h = t >> 5;
#pragma unroll
  for (int r = 0; r < 8; ++r) {
    int row = base + r;
    if (row < n) hp[(size_t)row * 128 + t] = acc[r];
    float vS = acc[r] * sA;
    float vD = acc[r] * sD;
#pragma unroll
    for (int off = 1; off < 32; off <<= 1) {
      vS += __shfl_xor(vS, off);
      vD += __shfl_xor(vD, off);
    }
    if ((t & 31) == 0 && row < n) {
      ls[(size_t)row * 4 + h] = vS;
      ldv[(size_t)row * 4 + h] = vD;
    }
  }
}

// ---------- wave-per-node aggregation with LDS-cached logits ----------
__global__ __launch_bounds__(256) void agg_kernel(
    const float* __restrict__ hp, const float* __restrict__ ls,
    const float* __restrict__ ldv, const float* __restrict__ le,
    const int* __restrict__ rowptr, const int* __restrict__ esrc,
    const int* __restrict__ eeid, const float* __restrict__ bias,
    float* __restrict__ out, int n, int do_elu) {
  __shared__ float gall[4][DEG_CAP * 4];  // per-wave logit/alpha slab (8 KB)
  float* gl = gall[threadIdx.x >> 6];
  int wid = (blockIdx.x * blockDim.x + threadIdx.x) >> 6;
  int lane = threadIdx.x & 63;
  if (wid >= n) return;
  int lo = rowptr[wid], hi = rowptr[wid + 1];
  int deg = hi - lo;
  float4 ldn = *(const float4*)(ldv + (size_t)wid * 4);
  int h = lane >> 4;  // head for gather phase: lane covers cols [2*lane,2*lane+1]
  int col = lane * 2;
  float ldh = h == 0 ? ldn.x : (h == 1 ? ldn.y : (h == 2 ? ldn.z : ldn.w));
  float a0 = 0.f, a1 = 0.f;

  if (deg <= DEG_CAP) {
    // pass 1: compute logits (vectorized), stash in LDS, track max only
    float m0 = -1e30f, m1 = -1e30f, m2 = -1e30f, m3 = -1e30f;
    for (int e = lo + lane, j = lane; e < hi; e += 64, j += 64) {
      int src = esrc[e];
      int id = eeid[e];
      float4 lsv = *(const float4*)(ls + (size_t)src * 4);
      float4 lev = *(const float4*)(le + (size_t)id * 4);
      float g0 = lsv.x + ldn.x + lev.x; g0 = g0 > 0.f ? g0 : 0.2f * g0;
      float g1 = lsv.y + ldn.y + lev.y; g1 = g1 > 0.f ? g1 : 0.2f * g1;
      float g2 = lsv.z + ldn.z + lev.z; g2 = g2 > 0.f ? g2 : 0.2f * g2;
      float g3 = lsv.w + ldn.w + lev.w; g3 = g3 > 0.f ? g3 : 0.2f * g3;
      ((float4*)gl)[j] = make_float4(g0, g1, g2, g3);
      m0 = fmaxf(m0, g0); m1 = fmaxf(m1, g1); m2 = fmaxf(m2, g2); m3 = fmaxf(m3, g3);
    }
#pragma unroll
    for (int off = 1; off < 64; off <<= 1) {
      m0 = fmaxf(m0, __shfl_xor(m0, off));
      m1 = fmaxf(m1, __shfl_xor(m1, off));
      m2 = fmaxf(m2, __shfl_xor(m2, off));
      m3 = fmaxf(m3, __shfl_xor(m3, off));
    }
    if (m0 < -1e29f) m0 = 0.f;
    if (m1 < -1e29f) m1 = 0.f;
    if (m2 < -1e29f) m2 = 0.f;
    if (m3 < -1e29f) m3 = 0.f;
    float mh = h == 0 ? m0 : (h == 1 ? m1 : (h == 2 ? m2 : m3));

    // phase A: alpha = exp(g - m) once per (edge, head); partial sums per lane
    float sacc = 0.f;
    int je = lane & 15;
    for (int j0 = 0; j0 < deg; j0 += 16) {
      int j = j0 + je;
      if (j < deg) {
        float g = gl[j * 4 + h];
        float a = __expf(g - mh);
        gl[j * 4 + h] = a;
        sacc += a;
      }
    }
#pragma unroll
    for (int off = 1; off < 16; off <<= 1) sacc += __shfl_xor(sacc, off);
    float rdh = 1.0f / (sacc + 1e-16f);

    // phase B: gather hp rows, weight by LDS alpha (normalize at the end)
    for (int e = lo, j = 0; e < hi; ++e, ++j) {
      int src = esrc[e];
      float alpha = gl[j * 4 + h];
      float2 v = *(const float2*)(hp + (size_t)src * 128 + col);
      a0 += alpha * v.x;
      a1 += alpha * v.y;
    }
    a0 *= rdh;
    a1 *= rdh;
  } else {
    // slow path (deg > DEG_CAP): online softmax + recompute gather
    float m0 = -1e30f, m1 = -1e30f, m2 = -1e30f, m3 = -1e30f;
    float s0 = 0.f, s1 = 0.f, s2 = 0.f, s3 = 0.f;
    for (int e = lo + lane; e < hi; e += 64) {
      int src = esrc[e];
      int id = eeid[e];
      float4 lsv = *(const float4*)(ls + (size_t)src * 4);
      float4 lev = *(const float4*)(le + (size_t)id * 4);
      float g0 = lsv.x + ldn.x + lev.x; g0 = g0 > 0.f ? g0 : 0.2f * g0;
      float g1 = lsv.y + ldn.y + lev.y; g1 = g1 > 0.f ? g1 : 0.2f * g1;
      float g2 = lsv.z + ldn.z + lev.z; g2 = g2 > 0.f ? g2 : 0.2f * g2;
      float g3 = lsv.w + ldn.w + lev.w; g3 = g3 > 0.f ? g3 : 0.2f * g3;
      float nm;
      nm = fmaxf(m0, g0); s0 = s0 * __expf(m0 - nm) + __expf(g0 - nm); m0 = nm;
      nm = fmaxf(m1, g1); s1 = s1 * __expf(m1 - nm) + __expf(g1 - nm); m1 = nm;
      nm = fmaxf(m2, g2); s2 = s2 * __expf(m2 - nm) + __expf(g2 - nm); m2 = nm;
      nm = fmaxf(m3, g3); s3 = s3 * __expf(m3 - nm) + __expf(g3 - nm); m3 = nm;
    }
#pragma unroll
    for (int off = 1; off < 64; off <<= 1) {
      float om, os, nm;
      om = __shfl_xor(m0, off); os = __shfl_xor(s0, off);
      nm = fmaxf(m0, om); s0 = s0 * __expf(m0 - nm) + os * __expf(om - nm); m0 = nm;
      om = __shfl_xor(m1, off); os = __shfl_xor(s1, off);
      nm = fmaxf(m1, om); s1 = s1 * __expf(m1 - nm) + os * __expf(om - nm); m1 = nm;
      om = __shfl_xor(m2, off); os = __shfl_xor(s2, off);
      nm = fmaxf(m2, om); s2 = s2 * __expf(m2 - nm) + os * __expf(om - nm); m2 = nm;
      om = __shfl_xor(m3, off); os = __shfl_xor(s3, off);
      nm = fmaxf(m3, om); s3 = s3 * __expf(m3 - nm) + os * __expf(om - nm); m3 = nm;
    }
    if (m0 < -1e29f) m0 = 0.f;
    if (m1 < -1e29f) m1 = 0.f;
    if (m2 < -1e29f) m2 = 0.f;
    if (m3 < -1e29f) m3 = 0.f;
    s0 += 1e-16f; s1 += 1e-16f; s2 += 1e-16f; s3 += 1e-16f;
    float mh = h == 0 ? m0 : (h == 1 ? m1 : (h == 2 ? m2 : m3));
    float rdh = 1.0f / (h == 0 ? s0 : (h == 1 ? s1 : (h == 2 ? s2 : s3)));
    for (int e = lo; e < hi; ++e) {
      int src = esrc[e];
      int id = eeid[e];
      float g = ls[(size_t)src * 4 + h] + ldh + le[(size_t)id * 4 + h];
      g = g > 0.f ? g : 0.2f * g;
      float alpha = __expf(g - mh) * rdh;
      float2 v = *(const float2*)(hp + (size_t)src * 128 + col);
      a0 += alpha * v.x;
      a1 += alpha * v.y;
    }
  }

  float o0 = a0 + bias[col];
  float o1 = a1 + bias[col + 1];
  if (do_elu) {
    o0 = o0 > 0.f ? o0 : expm1f(o0);
    o1 = o1 > 0.f ? o1 : expm1f(o1);
  }
  *(float2*)(out + (size_t)wid * 128 + col) = make_float2(o0, o1);
}

// ---------- loc head: register-tiled GEMM  out[n] = relu(h@Wl1+bl1).Wl2+bl2 --
__global__ __launch_bounds__(256) void loc_kernel(
    const float* __restrict__ h, const float* __restrict__ Wl1,
    const float* __restrict__ bl1, const float* __restrict__ Wl2,
    const float* __restrict__ bl2, float* __restrict__ out, int n) {
  __shared__ float hs[32][68];   // [k][node], pad 68 keeps b128 alignment
  __shared__ float ws[32][68];   // [k][hid]
  int t = threadIdx.x;
  int tx = t & 15;   // hid tile: hids tx*4..tx*4+3
  int ty = t >> 4;   // node tile: nodes ty*4..ty*4+3
  int nbase = blockIdx.x * 64;
  float acc[4][4];
#pragma unroll
  for (int i = 0; i < 4; ++i)
#pragma unroll
    for (int j = 0; j < 4; ++j) acc[i][j] = 0.f;

  for (int kc = 0; kc < 128; kc += 32) {
    __syncthreads();
    {
      int row = t >> 2;        // 0..63
      int q = t & 3;           // quads q and q+4 of this row's 8 quads
      int node = nbase + row;
      float4 v0 = make_float4(0.f, 0.f, 0.f, 0.f);
      float4 v1 = v0;
      if (node < n) {
        const float4* src = (const float4*)(h + (size_t)node * 128 + kc);
        v0 = src[q];
        v1 = src[q + 4];
      }
      int k0 = q * 4;
      hs[k0 + 0][row] = v0.x; hs[k0 + 1][row] = v0.y;
      hs[k0 + 2][row] = v0.z; hs[k0 + 3][row] = v0.w;
      hs[k0 + 16][row] = v1.x; hs[k0 + 17][row] = v1.y;
      hs[k0 + 18][row] = v1.z; hs[k0 + 19][row] = v1.w;
    }
    {
      const float4* wsrc = (const float4*)(Wl1 + kc * 64);
#pragma unroll
      for (int q = 0; q < 2; ++q) {
        int idx = q * 256 + t;          // float4 index 0..511
        float4 v = wsrc[idx];
        int k = idx >> 4;               // 16 float4 per k-row
        int hid = (idx & 15) * 4;
        *(float4*)&ws[k][hid] = v;
      }
    }
    __syncthreads();
#pragma unroll
    for (int k = 0; k < 32; ++k) {
      float4 hv = *(const float4*)&hs[k][ty * 4];
      float4 wv = *(const float4*)&ws[k][tx * 4];
      acc[0][0] += hv.x * wv.x; acc[0][1] += hv.x * wv.y;
      acc[0][2] += hv.x * wv.z; acc[0][3] += hv.x * wv.w;
      acc[1][0] += hv.y * wv.x; acc[1][1] += hv.y * wv.y;
      acc[1][2] += hv.y * wv.z; acc[1][3] += hv.y * wv.w;
      acc[2][0] += hv.z * wv.x; acc[2][1] += hv.z * wv.y;
      acc[2][2] += hv.z * wv.z; acc[2][3] += hv.z * wv.w;
      acc[3][0] += hv.w * wv.x; acc[3][1] += hv.w * wv.y;
      acc[3][2] += hv.w * wv.z; acc[3][3] += hv.w * wv.w;
    }
  }
  float4 b1 = *(const float4*)(bl1 + tx * 4);
  float4 w2 = *(const float4*)(Wl2 + tx * 4);
  float b2v = bl2[0];
#pragma unroll
  for (int i = 0; i < 4; ++i) {
    float s = fmaxf(acc[i][0] + b1.x, 0.f) * w2.x +
              fmaxf(acc[i][1] + b1.y, 0.f) * w2.y +
              fmaxf(acc[i][2] + b1.z, 0.f) * w2.z +
              fmaxf(acc[i][3] + b1.w, 0.f) * w2.w;
#pragma unroll
    for (int off = 1; off < 16; off <<= 1) s += __shfl_xor(s, off);
    int node = nbase + ty * 4 + i;
    if (tx == 0 && node < n) out[node] = s + b2v;
  }
}

// ---------- class head: zero -> parallel segment-sum pool -> tiny MLP ----------
__global__ void zero_gemb_kernel(float* gemb) {
  int i = blockIdx.x * blockDim.x + threadIdx.x;
  if (i < 64 * 128) gemb[i] = 0.f;
}

__global__ __launch_bounds__(128) void pool_kernel(
    const float* __restrict__ h, const int* __restrict__ batch,
    float* __restrict__ gemb, int n) {
  int t = threadIdx.x;
  int base = blockIdx.x * 128;
  int end = base + 128 < n ? base + 128 : n;
  float acc = 0.f;
  int cur = -1;
  for (int node = base; node < end; ++node) {
    int g = batch[node];
    if (g != cur) {
      if (cur >= 0) atomicAdd(&gemb[cur * 128 + t], acc);
      acc = 0.f;
      cur = g;
    }
    acc += h[(size_t)node * 128 + t];
  }
  if (cur >= 0) atomicAdd(&gemb[cur * 128 + t], acc);
}

__global__ __launch_bounds__(128) void class_mlp_kernel(
    const float* __restrict__ gsum, const int* __restrict__ batch,
    const float* __restrict__ Wc1, const float* __restrict__ bc1,
    const float* __restrict__ Wc2, const float* __restrict__ bc2,
    float* __restrict__ out, int n) {
  int g = blockIdx.x;
  int t = threadIdx.x;
  int lo = 0, hi = n;
  while (lo < hi) { int mid = (lo + hi) >> 1; if (batch[mid] < g) lo = mid + 1; else hi = mid; }
  int a = lo, b2 = n;
  while (a < b2) { int mid = (a + b2) >> 1; if (batch[mid] < g + 1) a = mid + 1; else b2 = mid; }
  int cnt = a - lo;
  float denom = cnt > 0 ? (float)cnt : 1.f;
  __shared__ float gemb[128];
  __shared__ float hidl[128];
  gemb[t] = gsum[g * 128 + t] / denom;
  __syncthreads();
  float hid = bc1[t];
  for (int k = 0; k < 128; ++k) hid += gemb[k] * Wc1[k * 128 + t];
  hidl[t] = fmaxf(hid, 0.f);
  __syncthreads();
  if (t < 10) {
    float o = bc2[t];
    for (int k = 0; k < 128; ++k) o += hidl[k] * Wc2[k * 10 + t];
    out[g * 10 + t] = o;
  }
}

extern "C" void kernel_launch(void* const* d_in, const int* in_sizes, int n_in,
                              void* d_out, int out_size, void* d_ws, size_t ws_size,
                              hipStream_t stream) {
  const float* x = (const float*)d_in[0];
  const int* ei = (const int*)d_in[1];
  const float* ea = (const float*)d_in[2];
  const int* batch = (const int*)d_in[3];
  const float* W[3]  = {(const float*)d_in[4],  (const float*)d_in[10], (const float*)d_in[16]};
  const float* aS[3] = {(const float*)d_in[5],  (const float*)d_in[11], (const float*)d_in[17]};
  const float* aD[3] = {(const float*)d_in[6],  (const float*)d_in[12], (const float*)d_in[18]};
  const float* We[3] = {(const float*)d_in[7],  (const float*)d_in[13], (const float*)d_in[19]};
  const float* aE[3] = {(const float*)d_in[8],  (const float*)d_in[14], (const float*)d_in[20]};
  const float* bb[3] = {(const float*)d_in[9],  (const float*)d_in[15], (const float*)d_in[21]};
  const float* Wc1 = (const float*)d_in[22];
  const float* bc1 = (const float*)d_in[23];
  const float* Wc2 = (const float*)d_in[24];
  const float* bc2 = (const float*)d_in[25];
  const float* Wl1 = (const float*)d_in[26];
  const float* bl1 = (const float*)d_in[27];
  const float* Wl2 = (const float*)d_in[28];
  const float* bl2 = (const float*)d_in[29];

  const int N = in_sizes[0] / 64;
  const int E = in_sizes[1] / 2;
  const int EP = E + N;
  const int NBE = (E + 255) / 256;  // le_all blocks

  char* p = (char*)d_ws;
  auto alloc = [&](size_t bytes) {
    char* r = p;
    p += (bytes + 255) & ~(size_t)255;
    return r;
  };
  float* A      = (float*)alloc((size_t)N * 128 * 4);  // layer io
  float* hp     = (float*)alloc((size_t)N * 128 * 4);  // projected features
  float* ls     = (float*)alloc((size_t)N * 4 * 4);
  float* ldv    = (float*)alloc((size_t)N * 4 * 4);
  float* le0    = (float*)alloc((size_t)(E + 1) * 4 * 4);  // row E = self-loop le
  int* rowptr   = (int*)alloc((size_t)(N + 1) * 4);
  int* cursor   = (int*)alloc((size_t)N * 4);
  int* bsum     = (int*)alloc(256 * 4);
  int* esrc     = (int*)alloc((size_t)EP * 4);
  int* eeid     = (int*)alloc((size_t)EP * 4);
  float* m_acc  = (float*)alloc(16 * 4);
  float* gemb   = (float*)alloc(64 * 128 * 4);
  float* m_part = (float*)alloc((size_t)NBE * 16 * 4);
  // optional extra le slabs for the fused 3-layer edge pass
  size_t le_bytes = (((size_t)(E + 1) * 4 * 4) + 255) & ~(size_t)255;
  float* le1 = nullptr;
  float* le2 = nullptr;
  if ((size_t)(p - (char*)d_ws) + 2 * le_bytes <= ws_size) {
    le1 = (float*)alloc((size_t)(E + 1) * 4 * 4);
    le2 = (float*)alloc((size_t)(E + 1) * 4 * 4);
  }

  float* out_cls = (float*)d_out;
  float* out_loc = (float*)d_out + 640;

  int nb = (N + SCAN_TILE - 1) / SCAN_TILE;

  init_cnt_kernel<<<(N + 255) / 256, 256, 0, stream>>>(cursor, m_acc, N);
  count_kernel<<<1024, 256, 0, stream>>>(ei + E, cursor, E);
  scan1_kernel<<<nb, 256, 0, stream>>>(cursor, rowptr, bsum, N);
  scan2_kernel<<<1, 64, 0, stream>>>(bsum, nb, rowptr);
  scan3_kernel<<<nb, 256, 0, stream>>>(bsum, rowptr, cursor, N);
  scatter_kernel<<<2048, 256, 0, stream>>>(ei, cursor, esrc, eeid, E, N);

  if (le1) {
    le_all_kernel<<<NBE, 256, 0, stream>>>(ea, We[0], aE[0], We[1], aE[1],
                                           We[2], aE[2], le0, le1, le2, m_part, E);
    le_mean_reduce_kernel<<<1, 256, 0, stream>>>(m_part, m_acc, NBE);
    le_self_all_kernel<<<1, 64, 0, stream>>>(m_acc, 1.0f / (float)E,
                                             We[0], aE[0], We[1], aE[1],
                                             We[2], aE[2], le0, le1, le2, E);
  }

  for (int l = 0; l < 3; ++l) {
    float* leL = l == 0 ? le0 : (l == 1 ? (le1 ? le1 : le0) : (le2 ? le2 : le0));
    if (!le1) {  // fallback: per-layer le into le0
      if (l == 0)
        le_kernel<true><<<2048, 256, 0, stream>>>(ea, We[0], aE[0], le0, m_acc, E);
      else
        le_kernel<false><<<2048, 256, 0, stream>>>(ea, We[l], aE[l], le0, nullptr, E);
      le_self_kernel<<<1, 64, 0, stream>>>(m_acc, 1.0f / (float)E, We[l], aE[l], le0, E);
    }
    if (l == 0)
      proj_kernel<64><<<(N + 7) / 8, 128, 0, stream>>>(x, W[0], aS[0], aD[0], hp, ls, ldv, N);
    else
      proj_kernel<128><<<(N + 7) / 8, 128, 0, stream>>>(A, W[l], aS[l], aD[l], hp, ls, ldv, N);
    agg_kernel<<<(N * 64 + 255) / 256, 256, 0, stream>>>(
        hp, ls, ldv, leL, rowptr, esrc, eeid, bb[l], A, N, l < 2 ? 1 : 0);
  }

  loc_kernel<<<(N + 63) / 64, 256, 0, stream>>>(A, Wl1, bl1, Wl2, bl2, out_loc, N);
  zero_gemb_kernel<<<32, 256, 0, stream>>>(gemb);
  pool_kernel<<<(N + 127) / 128, 128, 0, stream>>>(A, batch, gemb, N);
  class_mlp_kernel<<<64, 128, 0, stream>>>(gemb, batch, Wc1, bc1, Wc2, bc2, out_cls, N);
}